// Round 1
// baseline (623.953 us; speedup 1.0000x reference)
//
#include <hip/hip_runtime.h>
#include <hip/hip_bf16.h>
#include <math.h>

// ---------------------------------------------------------------------------
// GAT 2-layer forward, fp32 baseline.
// Layer0: h0 = x@W0 [N,256]; alpha; CSR-gather softmax-aggregate; +b0; ELU -> x1
// Layer1: h1 = x1@W1 [N,64]; alpha; CSR-gather softmax-aggregate; +b1 -> out
// ---------------------------------------------------------------------------

#define NEG_SLOPE 0.2f

// ------------------------- CSR build -------------------------

__global__ void gat_count_kernel(const int* __restrict__ dst, int E, int N,
                                 int* __restrict__ counts) {
  int i = blockIdx.x * blockDim.x + threadIdx.x;
  int ET = E + N;
  if (i >= ET) return;
  int d = (i < E) ? dst[i] : (i - E);
  atomicAdd(&counts[d], 1);
}

// single-block exclusive scan, 1024 threads, 4 elems/thread/tile
__global__ __launch_bounds__(1024) void gat_scan_kernel(
    const int* __restrict__ counts, int* __restrict__ row_off,
    int* __restrict__ cursor, int n) {
  __shared__ int wsum[16];
  __shared__ int s_carry;
  int tid = threadIdx.x;
  int lane = tid & 63;
  int wid = tid >> 6;
  if (tid == 0) s_carry = 0;
  __syncthreads();
  const int TILE = 4096;
  for (int base = 0; base < n; base += TILE) {
    int idx = base + tid * 4;
    int4 v = {0, 0, 0, 0};
    if (idx + 3 < n) {
      v = *(const int4*)&counts[idx];
    } else {
      if (idx + 0 < n) v.x = counts[idx + 0];
      if (idx + 1 < n) v.y = counts[idx + 1];
      if (idx + 2 < n) v.z = counts[idx + 2];
      if (idx + 3 < n) v.w = counts[idx + 3];
    }
    int t0 = v.x, t1 = t0 + v.y, t2 = t1 + v.z, t3 = t2 + v.w;
    int x = t3;
    #pragma unroll
    for (int off = 1; off < 64; off <<= 1) {
      int y = __shfl_up(x, off, 64);
      if (lane >= off) x += y;
    }
    if (lane == 63) wsum[wid] = x;
    __syncthreads();
    if (tid < 16) {
      int s = wsum[tid];
      #pragma unroll
      for (int off = 1; off < 16; off <<= 1) {
        int y = __shfl_up(s, off, 16);
        if (tid >= off) s += y;
      }
      wsum[tid] = s;
    }
    __syncthreads();
    int carry = s_carry;
    int excl_wave = (wid > 0) ? wsum[wid - 1] : 0;
    int b = carry + excl_wave + (x - t3);
    if (idx + 0 < n) { row_off[idx + 0] = b;      cursor[idx + 0] = b;      }
    if (idx + 1 < n) { row_off[idx + 1] = b + t0; cursor[idx + 1] = b + t0; }
    if (idx + 2 < n) { row_off[idx + 2] = b + t1; cursor[idx + 2] = b + t1; }
    if (idx + 3 < n) { row_off[idx + 3] = b + t2; cursor[idx + 3] = b + t2; }
    __syncthreads();
    if (tid == 1023) s_carry = b + t3;  // carry + tile total
    __syncthreads();
  }
  if (threadIdx.x == 0) row_off[n] = s_carry;
}

__global__ void gat_fill_kernel(const int* __restrict__ src,
                                const int* __restrict__ dst, int E, int N,
                                int* __restrict__ cursor, int* __restrict__ col) {
  int i = blockIdx.x * blockDim.x + threadIdx.x;
  int ET = E + N;
  if (i >= ET) return;
  int s, d;
  if (i < E) { s = src[i]; d = dst[i]; }
  else       { s = d = i - E; }
  int pos = atomicAdd(&cursor[d], 1);
  col[pos] = s;
}

// ------------------------- GEMM (f32, tiled) -------------------------
// C[N,M] = A[N,K] @ B[K,M], row-major. BM=BN=64, BK=16, 256 thr, 4x4/thr.

__global__ __launch_bounds__(256) void gat_gemm_f32(
    const float* __restrict__ A, const float* __restrict__ B,
    float* __restrict__ C, int N, int K, int M) {
  __shared__ float As[16][64];
  __shared__ float Bs[16][68];
  int tid = threadIdx.x;
  int brow = blockIdx.y * 64;
  int bcol = blockIdx.x * 64;
  int rowA = tid >> 2;
  int kA = (tid & 3) * 4;
  int kB = tid >> 4;
  int mB = (tid & 15) * 4;
  int trow = (tid >> 4) * 4;
  int tcol = (tid & 15) * 4;
  float acc[4][4] = {};
  for (int k0 = 0; k0 < K; k0 += 16) {
    float4 av = make_float4(0.f, 0.f, 0.f, 0.f);
    int ar = brow + rowA;
    if (ar < N) av = *(const float4*)&A[(size_t)ar * K + k0 + kA];
    As[kA + 0][rowA] = av.x;
    As[kA + 1][rowA] = av.y;
    As[kA + 2][rowA] = av.z;
    As[kA + 3][rowA] = av.w;
    float4 bv = *(const float4*)&B[(size_t)(k0 + kB) * M + bcol + mB];
    *(float4*)&Bs[kB][mB] = bv;
    __syncthreads();
    #pragma unroll
    for (int kk = 0; kk < 16; ++kk) {
      float4 a4 = *(const float4*)&As[kk][trow];
      float4 b4 = *(const float4*)&Bs[kk][tcol];
      float a[4] = {a4.x, a4.y, a4.z, a4.w};
      float b[4] = {b4.x, b4.y, b4.z, b4.w};
      #pragma unroll
      for (int i = 0; i < 4; ++i)
        #pragma unroll
        for (int j = 0; j < 4; ++j)
          acc[i][j] = fmaf(a[i], b[j], acc[i][j]);
    }
    __syncthreads();
  }
  #pragma unroll
  for (int i = 0; i < 4; ++i) {
    int r = brow + trow + i;
    if (r < N) {
      float4 o = make_float4(acc[i][0], acc[i][1], acc[i][2], acc[i][3]);
      *(float4*)&C[(size_t)r * M + bcol + tcol] = o;
    }
  }
}

// ------------------------- alpha = <h, a_src/a_dst> -------------------------
// one wave per (node, head); block = 4 waves

__global__ __launch_bounds__(256) void gat_alpha_kernel(
    const float* __restrict__ h, const float* __restrict__ a_src,
    const float* __restrict__ a_dst, float* __restrict__ as_out,
    float* __restrict__ ad_out, int N, int H) {
  int lane = threadIdx.x & 63;
  int wid = threadIdx.x >> 6;
  int g = blockIdx.x * 4 + wid;  // = n*H + h
  if (g >= N * H) return;
  int hh = g % H;
  float v = h[(size_t)g * 64 + lane];  // h[n, hh*64 + lane] since g*64 = n*H*64 + hh*64
  float s = v * a_src[hh * 64 + lane];
  float d = v * a_dst[hh * 64 + lane];
  #pragma unroll
  for (int off = 32; off; off >>= 1) {
    s += __shfl_xor(s, off, 64);
    d += __shfl_xor(d, off, 64);
  }
  if (lane == 0) {
    as_out[g] = s;
    ad_out[g] = d;
  }
}

// ------------------------- layer-0 aggregation -------------------------
// one block (256 thr) per node; wave = head; lane = d

__global__ __launch_bounds__(256) void gat_agg0_kernel(
    const float* __restrict__ h0, const float* __restrict__ as,
    const float* __restrict__ ad, const int* __restrict__ row_off,
    const int* __restrict__ col, const float* __restrict__ bias,
    float* __restrict__ x1, int N) {
  int n = blockIdx.x;
  int lane = threadIdx.x & 63;
  int h = threadIdx.x >> 6;
  int beg = row_off[n];
  int end = row_off[n + 1];
  float adv = ad[n * 4 + h];

  float m = -INFINITY;
  for (int j = beg + lane; j < end; j += 64) {
    float e = as[col[j] * 4 + h] + adv;
    e = (e > 0.f) ? e : NEG_SLOPE * e;
    m = fmaxf(m, e);
  }
  #pragma unroll
  for (int off = 32; off; off >>= 1) m = fmaxf(m, __shfl_xor(m, off, 64));

  float dsum = 0.f;
  for (int j = beg + lane; j < end; j += 64) {
    float e = as[col[j] * 4 + h] + adv;
    e = (e > 0.f) ? e : NEG_SLOPE * e;
    dsum += __expf(e - m);
  }
  #pragma unroll
  for (int off = 32; off; off >>= 1) dsum += __shfl_xor(dsum, off, 64);
  float inv = 1.f / (dsum + 1e-16f);

  float acc = 0.f;
  for (int j = beg; j < end; ++j) {
    int s = col[j];
    float e = as[s * 4 + h] + adv;
    e = (e > 0.f) ? e : NEG_SLOPE * e;
    float w = __expf(e - m) * inv;
    acc = fmaf(w, h0[(size_t)s * 256 + h * 64 + lane], acc);
  }
  float o = acc + bias[h * 64 + lane];
  o = (o > 0.f) ? o : (__expf(o) - 1.f);  // ELU
  x1[(size_t)n * 256 + h * 64 + lane] = o;
}

// ------------------------- layer-1 aggregation -------------------------
// one wave per node (H=1, D=64); block = 4 nodes

__global__ __launch_bounds__(256) void gat_agg1_kernel(
    const float* __restrict__ h1, const float* __restrict__ as,
    const float* __restrict__ ad, const int* __restrict__ row_off,
    const int* __restrict__ col, const float* __restrict__ bias,
    float* __restrict__ out, int N) {
  int lane = threadIdx.x & 63;
  int wid = threadIdx.x >> 6;
  int n = blockIdx.x * 4 + wid;
  if (n >= N) return;
  int beg = row_off[n];
  int end = row_off[n + 1];
  float adv = ad[n];

  float m = -INFINITY;
  for (int j = beg + lane; j < end; j += 64) {
    float e = as[col[j]] + adv;
    e = (e > 0.f) ? e : NEG_SLOPE * e;
    m = fmaxf(m, e);
  }
  #pragma unroll
  for (int off = 32; off; off >>= 1) m = fmaxf(m, __shfl_xor(m, off, 64));

  float dsum = 0.f;
  for (int j = beg + lane; j < end; j += 64) {
    float e = as[col[j]] + adv;
    e = (e > 0.f) ? e : NEG_SLOPE * e;
    dsum += __expf(e - m);
  }
  #pragma unroll
  for (int off = 32; off; off >>= 1) dsum += __shfl_xor(dsum, off, 64);
  float inv = 1.f / (dsum + 1e-16f);

  float acc = 0.f;
  for (int j = beg; j < end; ++j) {
    int s = col[j];
    float e = as[s] + adv;
    e = (e > 0.f) ? e : NEG_SLOPE * e;
    float w = __expf(e - m) * inv;
    acc = fmaf(w, h1[(size_t)s * 64 + lane], acc);
  }
  out[(size_t)n * 64 + lane] = acc + bias[lane];
}

// ------------------------- launch -------------------------

extern "C" void kernel_launch(void* const* d_in, const int* in_sizes, int n_in,
                              void* d_out, int out_size, void* d_ws, size_t ws_size,
                              hipStream_t stream) {
  const float* x        = (const float*)d_in[0];
  const int*   eidx     = (const int*)d_in[1];
  const float* W0       = (const float*)d_in[2];
  const float* att_src0 = (const float*)d_in[3];
  const float* att_dst0 = (const float*)d_in[4];
  const float* b0       = (const float*)d_in[5];
  const float* W1       = (const float*)d_in[6];
  const float* att_src1 = (const float*)d_in[7];
  const float* att_dst1 = (const float*)d_in[8];
  const float* b1       = (const float*)d_in[9];
  float* out = (float*)d_out;

  const int F_IN = 256, HID = 256, H = 4, C = 64;
  const int N = in_sizes[0] / F_IN;       // 50000
  const int E = in_sizes[1] / 2;          // 800000
  const int ET = E + N;                   // with self-loops

  const int* src = eidx;
  const int* dst = eidx + E;

  // workspace layout
  char* w = (char*)d_ws;
  auto take = [&](size_t bytes) {
    char* p = w;
    w += (bytes + 255) & ~(size_t)255;
    return p;
  };
  float* h0      = (float*)take((size_t)N * HID * 4);
  float* x1      = (float*)take((size_t)N * HID * 4);
  float* h1      = (float*)take((size_t)N * C * 4);
  float* as0     = (float*)take((size_t)N * H * 4);
  float* ad0     = (float*)take((size_t)N * H * 4);
  float* as1     = (float*)take((size_t)N * 4);
  float* ad1     = (float*)take((size_t)N * 4);
  int*   row_off = (int*)take((size_t)(N + 1) * 4);
  int*   cursor  = (int*)take((size_t)N * 4);
  int*   counts  = (int*)take((size_t)N * 4);
  int*   col     = (int*)take((size_t)ET * 4);

  // --- CSR build ---
  hipMemsetAsync(counts, 0, (size_t)N * 4, stream);
  {
    int blocks = (ET + 255) / 256;
    gat_count_kernel<<<blocks, 256, 0, stream>>>(dst, E, N, counts);
    gat_scan_kernel<<<1, 1024, 0, stream>>>(counts, row_off, cursor, N);
    gat_fill_kernel<<<blocks, 256, 0, stream>>>(src, dst, E, N, cursor, col);
  }

  // --- layer 0 ---
  {
    dim3 grid(HID / 64, (N + 63) / 64);
    gat_gemm_f32<<<grid, 256, 0, stream>>>(x, W0, h0, N, F_IN, HID);
  }
  {
    int blocks = (N * H + 3) / 4;
    gat_alpha_kernel<<<blocks, 256, 0, stream>>>(h0, att_src0, att_dst0, as0, ad0, N, H);
  }
  gat_agg0_kernel<<<N, 256, 0, stream>>>(h0, as0, ad0, row_off, col, b0, x1, N);

  // --- layer 1 ---
  {
    dim3 grid(C / 64, (N + 63) / 64);
    gat_gemm_f32<<<grid, 256, 0, stream>>>(x1, W1, h1, N, HID, C);
  }
  {
    int blocks = (N * 1 + 3) / 4;
    gat_alpha_kernel<<<blocks, 256, 0, stream>>>(h1, att_src1, att_dst1, as1, ad1, N, 1);
  }
  gat_agg1_kernel<<<(N + 3) / 4, 256, 0, stream>>>(h1, as1, ad1, row_off, col, b1, out, N);
}

// Round 2
// 581.171 us; speedup vs baseline: 1.0736x; 1.0736x over previous
//
#include <hip/hip_runtime.h>
#include <hip/hip_bf16.h>
#include <math.h>

// ---------------------------------------------------------------------------
// GAT 2-layer forward, fp32.
// Layer0: h0 = x@W0 [N,256]; alpha; CSR-gather softmax-aggregate; +b0; ELU -> x1
// Layer1: h1 = x1@W1 [N,64]; alpha; CSR-gather softmax-aggregate; +b1 -> out
// R1: agg kernels restructured — weights cached in LDS, edge-parallel waves,
//     float4 row gathers, single LDS combine. (was: serial per-edge loop)
// ---------------------------------------------------------------------------

#define NEG_SLOPE 0.2f
#define CAP0 128
#define CAP1 128

// ------------------------- CSR build -------------------------

__global__ void gat_count_kernel(const int* __restrict__ dst, int E, int N,
                                 int* __restrict__ counts) {
  int i = blockIdx.x * blockDim.x + threadIdx.x;
  int ET = E + N;
  if (i >= ET) return;
  int d = (i < E) ? dst[i] : (i - E);
  atomicAdd(&counts[d], 1);
}

// single-block exclusive scan, 1024 threads, 4 elems/thread/tile
__global__ __launch_bounds__(1024) void gat_scan_kernel(
    const int* __restrict__ counts, int* __restrict__ row_off,
    int* __restrict__ cursor, int n) {
  __shared__ int wsum[16];
  __shared__ int s_carry;
  int tid = threadIdx.x;
  int lane = tid & 63;
  int wid = tid >> 6;
  if (tid == 0) s_carry = 0;
  __syncthreads();
  const int TILE = 4096;
  for (int base = 0; base < n; base += TILE) {
    int idx = base + tid * 4;
    int4 v = {0, 0, 0, 0};
    if (idx + 3 < n) {
      v = *(const int4*)&counts[idx];
    } else {
      if (idx + 0 < n) v.x = counts[idx + 0];
      if (idx + 1 < n) v.y = counts[idx + 1];
      if (idx + 2 < n) v.z = counts[idx + 2];
      if (idx + 3 < n) v.w = counts[idx + 3];
    }
    int t0 = v.x, t1 = t0 + v.y, t2 = t1 + v.z, t3 = t2 + v.w;
    int x = t3;
    #pragma unroll
    for (int off = 1; off < 64; off <<= 1) {
      int y = __shfl_up(x, off, 64);
      if (lane >= off) x += y;
    }
    if (lane == 63) wsum[wid] = x;
    __syncthreads();
    if (tid < 16) {
      int s = wsum[tid];
      #pragma unroll
      for (int off = 1; off < 16; off <<= 1) {
        int y = __shfl_up(s, off, 16);
        if (tid >= off) s += y;
      }
      wsum[tid] = s;
    }
    __syncthreads();
    int carry = s_carry;
    int excl_wave = (wid > 0) ? wsum[wid - 1] : 0;
    int b = carry + excl_wave + (x - t3);
    if (idx + 0 < n) { row_off[idx + 0] = b;      cursor[idx + 0] = b;      }
    if (idx + 1 < n) { row_off[idx + 1] = b + t0; cursor[idx + 1] = b + t0; }
    if (idx + 2 < n) { row_off[idx + 2] = b + t1; cursor[idx + 2] = b + t1; }
    if (idx + 3 < n) { row_off[idx + 3] = b + t2; cursor[idx + 3] = b + t2; }
    __syncthreads();
    if (tid == 1023) s_carry = b + t3;  // carry + tile total
    __syncthreads();
  }
  if (threadIdx.x == 0) row_off[n] = s_carry;
}

__global__ void gat_fill_kernel(const int* __restrict__ src,
                                const int* __restrict__ dst, int E, int N,
                                int* __restrict__ cursor, int* __restrict__ col) {
  int i = blockIdx.x * blockDim.x + threadIdx.x;
  int ET = E + N;
  if (i >= ET) return;
  int s, d;
  if (i < E) { s = src[i]; d = dst[i]; }
  else       { s = d = i - E; }
  int pos = atomicAdd(&cursor[d], 1);
  col[pos] = s;
}

// ------------------------- GEMM (f32, tiled) -------------------------
// C[N,M] = A[N,K] @ B[K,M], row-major. BM=BN=64, BK=16, 256 thr, 4x4/thr.

__global__ __launch_bounds__(256) void gat_gemm_f32(
    const float* __restrict__ A, const float* __restrict__ B,
    float* __restrict__ C, int N, int K, int M) {
  __shared__ float As[16][64];
  __shared__ float Bs[16][68];
  int tid = threadIdx.x;
  int brow = blockIdx.y * 64;
  int bcol = blockIdx.x * 64;
  int rowA = tid >> 2;
  int kA = (tid & 3) * 4;
  int kB = tid >> 4;
  int mB = (tid & 15) * 4;
  int trow = (tid >> 4) * 4;
  int tcol = (tid & 15) * 4;
  float acc[4][4] = {};
  for (int k0 = 0; k0 < K; k0 += 16) {
    float4 av = make_float4(0.f, 0.f, 0.f, 0.f);
    int ar = brow + rowA;
    if (ar < N) av = *(const float4*)&A[(size_t)ar * K + k0 + kA];
    As[kA + 0][rowA] = av.x;
    As[kA + 1][rowA] = av.y;
    As[kA + 2][rowA] = av.z;
    As[kA + 3][rowA] = av.w;
    float4 bv = *(const float4*)&B[(size_t)(k0 + kB) * M + bcol + mB];
    *(float4*)&Bs[kB][mB] = bv;
    __syncthreads();
    #pragma unroll
    for (int kk = 0; kk < 16; ++kk) {
      float4 a4 = *(const float4*)&As[kk][trow];
      float4 b4 = *(const float4*)&Bs[kk][tcol];
      float a[4] = {a4.x, a4.y, a4.z, a4.w};
      float b[4] = {b4.x, b4.y, b4.z, b4.w};
      #pragma unroll
      for (int i = 0; i < 4; ++i)
        #pragma unroll
        for (int j = 0; j < 4; ++j)
          acc[i][j] = fmaf(a[i], b[j], acc[i][j]);
    }
    __syncthreads();
  }
  #pragma unroll
  for (int i = 0; i < 4; ++i) {
    int r = brow + trow + i;
    if (r < N) {
      float4 o = make_float4(acc[i][0], acc[i][1], acc[i][2], acc[i][3]);
      *(float4*)&C[(size_t)r * M + bcol + tcol] = o;
    }
  }
}

// ------------------------- alpha = <h, a_src/a_dst> -------------------------
// one wave per (node, head); block = 4 waves

__global__ __launch_bounds__(256) void gat_alpha_kernel(
    const float* __restrict__ h, const float* __restrict__ a_src,
    const float* __restrict__ a_dst, float* __restrict__ as_out,
    float* __restrict__ ad_out, int N, int H) {
  int lane = threadIdx.x & 63;
  int wid = threadIdx.x >> 6;
  int g = blockIdx.x * 4 + wid;  // = n*H + h
  if (g >= N * H) return;
  int hh = g % H;
  float v = h[(size_t)g * 64 + lane];
  float s = v * a_src[hh * 64 + lane];
  float d = v * a_dst[hh * 64 + lane];
  #pragma unroll
  for (int off = 32; off; off >>= 1) {
    s += __shfl_xor(s, off, 64);
    d += __shfl_xor(d, off, 64);
  }
  if (lane == 0) {
    as_out[g] = s;
    ad_out[g] = d;
  }
}

// ------------------------- layer-0 aggregation -------------------------
// one block (256 thr) per node. Pass1/2: wave=head, lane strides edges,
// weights stashed in LDS. Pass3: waves split edges (mod 4), lane reads a
// float4 of the h0 row (channels lane*4..lane*4+3, head q=lane>>4),
// cross-wave LDS combine, then scale+bias+ELU.

__global__ __launch_bounds__(256) void gat_agg0_kernel(
    const float* __restrict__ h0, const float* __restrict__ as,
    const float* __restrict__ ad, const int* __restrict__ row_off,
    const int* __restrict__ col, const float* __restrict__ bias,
    float* __restrict__ x1, int N) {
  __shared__ float wt[4][CAP0];
  __shared__ float accbuf[4][256];
  __shared__ float sm_m[4];
  __shared__ float sm_inv[4];
  int n = blockIdx.x;
  int tid = threadIdx.x;
  int lane = tid & 63;
  int wid = tid >> 6;
  int beg = row_off[n];
  int end = row_off[n + 1];

  // pass 1: per-head running max (wave wid owns head wid)
  float adv = ad[n * 4 + wid];
  float m = -INFINITY;
  for (int j = beg + lane; j < end; j += 64) {
    float e = as[col[j] * 4 + wid] + adv;
    e = (e > 0.f) ? e : NEG_SLOPE * e;
    m = fmaxf(m, e);
  }
  #pragma unroll
  for (int off = 32; off; off >>= 1) m = fmaxf(m, __shfl_xor(m, off, 64));
  if (lane == 0) sm_m[wid] = m;

  // pass 2: denom + stash unnormalized weights
  float dsum = 0.f;
  for (int j = beg + lane; j < end; j += 64) {
    float e = as[col[j] * 4 + wid] + adv;
    e = (e > 0.f) ? e : NEG_SLOPE * e;
    float w = __expf(e - m);
    dsum += w;
    int jj = j - beg;
    if (jj < CAP0) wt[wid][jj] = w;
  }
  #pragma unroll
  for (int off = 32; off; off >>= 1) dsum += __shfl_xor(dsum, off, 64);
  if (lane == 0) sm_inv[wid] = 1.f / (dsum + 1e-16f);
  __syncthreads();

  // pass 3: edge-parallel weighted gather
  int q = lane >> 4;  // head of channels lane*4 .. lane*4+3
  float4 acc = make_float4(0.f, 0.f, 0.f, 0.f);
  for (int j = beg + wid; j < end; j += 4) {
    int s = col[j];
    float4 v = *(const float4*)&h0[(size_t)s * 256 + lane * 4];
    int jj = j - beg;
    float w;
    if (jj < CAP0) {
      w = wt[q][jj];
    } else {  // fallback, practically never taken (deg <= CAP0)
      float e = as[s * 4 + q] + ad[n * 4 + q];
      e = (e > 0.f) ? e : NEG_SLOPE * e;
      w = __expf(e - sm_m[q]);
    }
    acc.x = fmaf(w, v.x, acc.x);
    acc.y = fmaf(w, v.y, acc.y);
    acc.z = fmaf(w, v.z, acc.z);
    acc.w = fmaf(w, v.w, acc.w);
  }
  *(float4*)&accbuf[wid][lane * 4] = acc;
  __syncthreads();

  float o = accbuf[0][tid] + accbuf[1][tid] + accbuf[2][tid] + accbuf[3][tid];
  o = o * sm_inv[tid >> 6] + bias[tid];
  o = (o > 0.f) ? o : (__expf(o) - 1.f);  // ELU
  x1[(size_t)n * 256 + tid] = o;
}

// ------------------------- layer-1 aggregation -------------------------
// one block per node; all waves compute m/denom redundantly (cheap scalar
// reads); wave 0 stashes weights; waves split edges for the gather.

__global__ __launch_bounds__(256) void gat_agg1_kernel(
    const float* __restrict__ h1, const float* __restrict__ as,
    const float* __restrict__ ad, const int* __restrict__ row_off,
    const int* __restrict__ col, const float* __restrict__ bias,
    float* __restrict__ out, int N) {
  __shared__ float wt[CAP1];
  __shared__ float accbuf[4][64];
  int n = blockIdx.x;
  int tid = threadIdx.x;
  int lane = tid & 63;
  int wid = tid >> 6;
  int beg = row_off[n];
  int end = row_off[n + 1];
  float adv = ad[n];

  float m = -INFINITY;
  for (int j = beg + lane; j < end; j += 64) {
    float e = as[col[j]] + adv;
    e = (e > 0.f) ? e : NEG_SLOPE * e;
    m = fmaxf(m, e);
  }
  #pragma unroll
  for (int off = 32; off; off >>= 1) m = fmaxf(m, __shfl_xor(m, off, 64));

  float dsum = 0.f;
  for (int j = beg + lane; j < end; j += 64) {
    float e = as[col[j]] + adv;
    e = (e > 0.f) ? e : NEG_SLOPE * e;
    float w = __expf(e - m);
    dsum += w;
    int jj = j - beg;
    if (wid == 0 && jj < CAP1) wt[jj] = w;
  }
  #pragma unroll
  for (int off = 32; off; off >>= 1) dsum += __shfl_xor(dsum, off, 64);
  float inv = 1.f / (dsum + 1e-16f);
  __syncthreads();

  float acc = 0.f;
  for (int j = beg + wid; j < end; j += 4) {
    int s = col[j];
    float v = h1[(size_t)s * 64 + lane];
    int jj = j - beg;
    float w;
    if (jj < CAP1) {
      w = wt[jj];
    } else {
      float e = as[s] + adv;
      e = (e > 0.f) ? e : NEG_SLOPE * e;
      w = __expf(e - m);
    }
    acc = fmaf(w, v, acc);
  }
  accbuf[wid][lane] = acc;
  __syncthreads();

  if (tid < 64) {
    float o = accbuf[0][tid] + accbuf[1][tid] + accbuf[2][tid] + accbuf[3][tid];
    out[(size_t)n * 64 + tid] = o * inv + bias[tid];
  }
}

// ------------------------- launch -------------------------

extern "C" void kernel_launch(void* const* d_in, const int* in_sizes, int n_in,
                              void* d_out, int out_size, void* d_ws, size_t ws_size,
                              hipStream_t stream) {
  const float* x        = (const float*)d_in[0];
  const int*   eidx     = (const int*)d_in[1];
  const float* W0       = (const float*)d_in[2];
  const float* att_src0 = (const float*)d_in[3];
  const float* att_dst0 = (const float*)d_in[4];
  const float* b0       = (const float*)d_in[5];
  const float* W1       = (const float*)d_in[6];
  const float* att_src1 = (const float*)d_in[7];
  const float* att_dst1 = (const float*)d_in[8];
  const float* b1       = (const float*)d_in[9];
  float* out = (float*)d_out;

  const int F_IN = 256, HID = 256, H = 4, C = 64;
  const int N = in_sizes[0] / F_IN;       // 50000
  const int E = in_sizes[1] / 2;          // 800000
  const int ET = E + N;                   // with self-loops

  const int* src = eidx;
  const int* dst = eidx + E;

  // workspace layout
  char* w = (char*)d_ws;
  auto take = [&](size_t bytes) {
    char* p = w;
    w += (bytes + 255) & ~(size_t)255;
    return p;
  };
  float* h0      = (float*)take((size_t)N * HID * 4);
  float* x1      = (float*)take((size_t)N * HID * 4);
  float* h1      = (float*)take((size_t)N * C * 4);
  float* as0     = (float*)take((size_t)N * H * 4);
  float* ad0     = (float*)take((size_t)N * H * 4);
  float* as1     = (float*)take((size_t)N * 4);
  float* ad1     = (float*)take((size_t)N * 4);
  int*   row_off = (int*)take((size_t)(N + 1) * 4);
  int*   cursor  = (int*)take((size_t)N * 4);
  int*   counts  = (int*)take((size_t)N * 4);
  int*   col     = (int*)take((size_t)ET * 4);

  // --- CSR build ---
  hipMemsetAsync(counts, 0, (size_t)N * 4, stream);
  {
    int blocks = (ET + 255) / 256;
    gat_count_kernel<<<blocks, 256, 0, stream>>>(dst, E, N, counts);
    gat_scan_kernel<<<1, 1024, 0, stream>>>(counts, row_off, cursor, N);
    gat_fill_kernel<<<blocks, 256, 0, stream>>>(src, dst, E, N, cursor, col);
  }

  // --- layer 0 ---
  {
    dim3 grid(HID / 64, (N + 63) / 64);
    gat_gemm_f32<<<grid, 256, 0, stream>>>(x, W0, h0, N, F_IN, HID);
  }
  {
    int blocks = (N * H + 3) / 4;
    gat_alpha_kernel<<<blocks, 256, 0, stream>>>(h0, att_src0, att_dst0, as0, ad0, N, H);
  }
  gat_agg0_kernel<<<N, 256, 0, stream>>>(h0, as0, ad0, row_off, col, b0, x1, N);

  // --- layer 1 ---
  {
    dim3 grid(C / 64, (N + 63) / 64);
    gat_gemm_f32<<<grid, 256, 0, stream>>>(x1, W1, h1, N, HID, C);
  }
  {
    int blocks = (N * 1 + 3) / 4;
    gat_alpha_kernel<<<blocks, 256, 0, stream>>>(h1, att_src1, att_dst1, as1, ad1, N, 1);
  }
  gat_agg1_kernel<<<N, 256, 0, stream>>>(h1, as1, ad1, row_off, col, b1, out, N);
}

// Round 5
// 521.400 us; speedup vs baseline: 1.1967x; 1.1146x over previous
//
#include <hip/hip_runtime.h>
#include <hip/hip_bf16.h>
#include <math.h>

// ---------------------------------------------------------------------------
// GAT 2-layer forward, fp32 math, bf16-packed gather table for layer 0.
// R1: agg kernels restructured (edge-parallel waves, LDS weight cache).
// R2: col[] staged in LDS (kills per-edge address latency chain);
//     GEMM epilogue dual-stores bf16x2-packed h0; agg0 gathers 8B/lane bf16.
// R3/R4: resubmits (bench infra failures, no data).
// ---------------------------------------------------------------------------

#define NEG_SLOPE 0.2f
#define CAP0 128
#define CAP1 128

static __device__ __forceinline__ unsigned f2bf_rne(float f) {
  unsigned u = __float_as_uint(f);
  return (u + 0x7fffu + ((u >> 16) & 1u)) >> 16;  // round-to-nearest-even
}

// ------------------------- CSR build -------------------------

__global__ void gat_count_kernel(const int* __restrict__ dst, int E, int N,
                                 int* __restrict__ counts) {
  int i = blockIdx.x * blockDim.x + threadIdx.x;
  int ET = E + N;
  if (i >= ET) return;
  int d = (i < E) ? dst[i] : (i - E);
  atomicAdd(&counts[d], 1);
}

// single-block exclusive scan, 1024 threads, 4 elems/thread/tile
__global__ __launch_bounds__(1024) void gat_scan_kernel(
    const int* __restrict__ counts, int* __restrict__ row_off,
    int* __restrict__ cursor, int n) {
  __shared__ int wsum[16];
  __shared__ int s_carry;
  int tid = threadIdx.x;
  int lane = tid & 63;
  int wid = tid >> 6;
  if (tid == 0) s_carry = 0;
  __syncthreads();
  const int TILE = 4096;
  for (int base = 0; base < n; base += TILE) {
    int idx = base + tid * 4;
    int4 v = {0, 0, 0, 0};
    if (idx + 3 < n) {
      v = *(const int4*)&counts[idx];
    } else {
      if (idx + 0 < n) v.x = counts[idx + 0];
      if (idx + 1 < n) v.y = counts[idx + 1];
      if (idx + 2 < n) v.z = counts[idx + 2];
      if (idx + 3 < n) v.w = counts[idx + 3];
    }
    int t0 = v.x, t1 = t0 + v.y, t2 = t1 + v.z, t3 = t2 + v.w;
    int x = t3;
    #pragma unroll
    for (int off = 1; off < 64; off <<= 1) {
      int y = __shfl_up(x, off, 64);
      if (lane >= off) x += y;
    }
    if (lane == 63) wsum[wid] = x;
    __syncthreads();
    if (tid < 16) {
      int s = wsum[tid];
      #pragma unroll
      for (int off = 1; off < 16; off <<= 1) {
        int y = __shfl_up(s, off, 16);
        if (tid >= off) s += y;
      }
      wsum[tid] = s;
    }
    __syncthreads();
    int carry = s_carry;
    int excl_wave = (wid > 0) ? wsum[wid - 1] : 0;
    int b = carry + excl_wave + (x - t3);
    if (idx + 0 < n) { row_off[idx + 0] = b;      cursor[idx + 0] = b;      }
    if (idx + 1 < n) { row_off[idx + 1] = b + t0; cursor[idx + 1] = b + t0; }
    if (idx + 2 < n) { row_off[idx + 2] = b + t1; cursor[idx + 2] = b + t1; }
    if (idx + 3 < n) { row_off[idx + 3] = b + t2; cursor[idx + 3] = b + t2; }
    __syncthreads();
    if (tid == 1023) s_carry = b + t3;  // carry + tile total
    __syncthreads();
  }
  if (threadIdx.x == 0) row_off[n] = s_carry;
}

__global__ void gat_fill_kernel(const int* __restrict__ src,
                                const int* __restrict__ dst, int E, int N,
                                int* __restrict__ cursor, int* __restrict__ col) {
  int i = blockIdx.x * blockDim.x + threadIdx.x;
  int ET = E + N;
  if (i >= ET) return;
  int s, d;
  if (i < E) { s = src[i]; d = dst[i]; }
  else       { s = d = i - E; }
  int pos = atomicAdd(&cursor[d], 1);
  col[pos] = s;
}

// ------------------------- GEMM (f32, tiled) -------------------------
// C[N,M] = A[N,K] @ B[K,M], row-major. BM=BN=64, BK=16, 256 thr, 4x4/thr.
// Optionally also emits Cb = bf16x2-packed copy of C (for gather kernels).

__global__ __launch_bounds__(256) void gat_gemm_f32(
    const float* __restrict__ A, const float* __restrict__ B,
    float* __restrict__ C, unsigned* __restrict__ Cb, int N, int K, int M) {
  __shared__ float As[16][64];
  __shared__ float Bs[16][68];
  int tid = threadIdx.x;
  int brow = blockIdx.y * 64;
  int bcol = blockIdx.x * 64;
  int rowA = tid >> 2;
  int kA = (tid & 3) * 4;
  int kB = tid >> 4;
  int mB = (tid & 15) * 4;
  int trow = (tid >> 4) * 4;
  int tcol = (tid & 15) * 4;
  float acc[4][4] = {};
  for (int k0 = 0; k0 < K; k0 += 16) {
    float4 av = make_float4(0.f, 0.f, 0.f, 0.f);
    int ar = brow + rowA;
    if (ar < N) av = *(const float4*)&A[(size_t)ar * K + k0 + kA];
    As[kA + 0][rowA] = av.x;
    As[kA + 1][rowA] = av.y;
    As[kA + 2][rowA] = av.z;
    As[kA + 3][rowA] = av.w;
    float4 bv = *(const float4*)&B[(size_t)(k0 + kB) * M + bcol + mB];
    *(float4*)&Bs[kB][mB] = bv;
    __syncthreads();
    #pragma unroll
    for (int kk = 0; kk < 16; ++kk) {
      float4 a4 = *(const float4*)&As[kk][trow];
      float4 b4 = *(const float4*)&Bs[kk][tcol];
      float a[4] = {a4.x, a4.y, a4.z, a4.w};
      float b[4] = {b4.x, b4.y, b4.z, b4.w};
      #pragma unroll
      for (int i = 0; i < 4; ++i)
        #pragma unroll
        for (int j = 0; j < 4; ++j)
          acc[i][j] = fmaf(a[i], b[j], acc[i][j]);
    }
    __syncthreads();
  }
  #pragma unroll
  for (int i = 0; i < 4; ++i) {
    int r = brow + trow + i;
    if (r < N) {
      float4 o = make_float4(acc[i][0], acc[i][1], acc[i][2], acc[i][3]);
      *(float4*)&C[(size_t)r * M + bcol + tcol] = o;
      if (Cb) {
        uint2 p;
        p.x = f2bf_rne(o.x) | (f2bf_rne(o.y) << 16);
        p.y = f2bf_rne(o.z) | (f2bf_rne(o.w) << 16);
        *(uint2*)&Cb[(size_t)r * (M >> 1) + ((bcol + tcol) >> 1)] = p;
      }
    }
  }
}

// ------------------------- alpha = <h, a_src/a_dst> -------------------------

__global__ __launch_bounds__(256) void gat_alpha_kernel(
    const float* __restrict__ h, const float* __restrict__ a_src,
    const float* __restrict__ a_dst, float* __restrict__ as_out,
    float* __restrict__ ad_out, int N, int H) {
  int lane = threadIdx.x & 63;
  int wid = threadIdx.x >> 6;
  int g = blockIdx.x * 4 + wid;  // = n*H + h
  if (g >= N * H) return;
  int hh = g % H;
  float v = h[(size_t)g * 64 + lane];
  float s = v * a_src[hh * 64 + lane];
  float d = v * a_dst[hh * 64 + lane];
  #pragma unroll
  for (int off = 32; off; off >>= 1) {
    s += __shfl_xor(s, off, 64);
    d += __shfl_xor(d, off, 64);
  }
  if (lane == 0) {
    as_out[g] = s;
    ad_out[g] = d;
  }
}

// ------------------------- layer-0 aggregation -------------------------
// one block (256 thr) per node. col[] staged in LDS. Pass1: e -> LDS + max.
// Pass2: w = exp(e-m) in LDS + denom. Pass3: waves split edges (mod 4),
// lane reads uint2 (4 bf16 ch) of packed h0 row; LDS combine; scale+bias+ELU.

__global__ __launch_bounds__(256) void gat_agg0_kernel(
    const unsigned* __restrict__ h0b, const float* __restrict__ as,
    const float* __restrict__ ad, const int* __restrict__ row_off,
    const int* __restrict__ col, const float* __restrict__ bias,
    float* __restrict__ x1, int N) {
  __shared__ int scol[CAP0];
  __shared__ float wt[4][CAP0];
  __shared__ float accbuf[4][256];
  __shared__ float sm_m[4];
  __shared__ float sm_inv[4];
  int n = blockIdx.x;
  int tid = threadIdx.x;
  int lane = tid & 63;
  int wid = tid >> 6;
  int beg = row_off[n];
  int end = row_off[n + 1];
  int deg = end - beg;
  int degc = deg < CAP0 ? deg : CAP0;
  for (int jj = tid; jj < degc; jj += 256) scol[jj] = col[beg + jj];
  __syncthreads();

  // pass 1: e values (stashed) + per-head max (wave wid owns head wid)
  float adv = ad[n * 4 + wid];
  float m = -INFINITY;
  for (int jj = lane; jj < deg; jj += 64) {
    int s = (jj < CAP0) ? scol[jj] : col[beg + jj];
    float e = as[s * 4 + wid] + adv;
    e = (e > 0.f) ? e : NEG_SLOPE * e;
    if (jj < CAP0) wt[wid][jj] = e;
    m = fmaxf(m, e);
  }
  #pragma unroll
  for (int off = 32; off; off >>= 1) m = fmaxf(m, __shfl_xor(m, off, 64));

  // pass 2: w = exp(e-m) (stashed) + denom
  float dsum = 0.f;
  for (int jj = lane; jj < deg; jj += 64) {
    float e;
    if (jj < CAP0) {
      e = wt[wid][jj];
    } else {
      int s = col[beg + jj];
      e = as[s * 4 + wid] + adv;
      e = (e > 0.f) ? e : NEG_SLOPE * e;
    }
    float w = __expf(e - m);
    if (jj < CAP0) wt[wid][jj] = w;
    dsum += w;
  }
  #pragma unroll
  for (int off = 32; off; off >>= 1) dsum += __shfl_xor(dsum, off, 64);
  if (lane == 0) {
    sm_m[wid] = m;
    sm_inv[wid] = 1.f / (dsum + 1e-16f);
  }
  __syncthreads();

  // pass 3: edge-parallel weighted gather (bf16 rows, 8B/lane)
  int q = lane >> 4;  // head of channels lane*4 .. lane*4+3
  float4 acc = make_float4(0.f, 0.f, 0.f, 0.f);
  for (int jj = wid; jj < deg; jj += 4) {
    int s = (jj < CAP0) ? scol[jj] : col[beg + jj];
    uint2 v = *(const uint2*)(h0b + (size_t)s * 128 + lane * 2);
    float w;
    if (jj < CAP0) {
      w = wt[q][jj];
    } else {  // fallback, practically never taken
      float e = as[s * 4 + q] + ad[n * 4 + q];
      e = (e > 0.f) ? e : NEG_SLOPE * e;
      w = __expf(e - sm_m[q]);
    }
    float v0 = __uint_as_float(v.x << 16);
    float v1 = __uint_as_float(v.x & 0xffff0000u);
    float v2 = __uint_as_float(v.y << 16);
    float v3 = __uint_as_float(v.y & 0xffff0000u);
    acc.x = fmaf(w, v0, acc.x);
    acc.y = fmaf(w, v1, acc.y);
    acc.z = fmaf(w, v2, acc.z);
    acc.w = fmaf(w, v3, acc.w);
  }
  *(float4*)&accbuf[wid][lane * 4] = acc;
  __syncthreads();

  float o = accbuf[0][tid] + accbuf[1][tid] + accbuf[2][tid] + accbuf[3][tid];
  o = o * sm_inv[tid >> 6] + bias[tid];
  o = (o > 0.f) ? o : (__expf(o) - 1.f);  // ELU
  x1[(size_t)n * 256 + tid] = o;
}

// ------------------------- layer-1 aggregation -------------------------
// one block per node; col staged in LDS; all waves compute m/denom
// redundantly; wave 0 stashes weights; waves split edges for the gather.

__global__ __launch_bounds__(256) void gat_agg1_kernel(
    const float* __restrict__ h1, const float* __restrict__ as,
    const float* __restrict__ ad, const int* __restrict__ row_off,
    const int* __restrict__ col, const float* __restrict__ bias,
    float* __restrict__ out, int N) {
  __shared__ int scol[CAP1];
  __shared__ float wt[CAP1];
  __shared__ float accbuf[4][64];
  int n = blockIdx.x;
  int tid = threadIdx.x;
  int lane = tid & 63;
  int wid = tid >> 6;
  int beg = row_off[n];
  int end = row_off[n + 1];
  int deg = end - beg;
  int degc = deg < CAP1 ? deg : CAP1;
  for (int jj = tid; jj < degc; jj += 256) scol[jj] = col[beg + jj];
  __syncthreads();
  float adv = ad[n];

  float m = -INFINITY;
  for (int jj = lane; jj < deg; jj += 64) {
    int s = (jj < CAP1) ? scol[jj] : col[beg + jj];
    float e = as[s] + adv;
    e = (e > 0.f) ? e : NEG_SLOPE * e;
    m = fmaxf(m, e);
  }
  #pragma unroll
  for (int off = 32; off; off >>= 1) m = fmaxf(m, __shfl_xor(m, off, 64));

  float dsum = 0.f;
  for (int jj = lane; jj < deg; jj += 64) {
    int s = (jj < CAP1) ? scol[jj] : col[beg + jj];
    float e = as[s] + adv;
    e = (e > 0.f) ? e : NEG_SLOPE * e;
    float w = __expf(e - m);
    dsum += w;
    if (wid == 0 && jj < CAP1) wt[jj] = w;
  }
  #pragma unroll
  for (int off = 32; off; off >>= 1) dsum += __shfl_xor(dsum, off, 64);
  float inv = 1.f / (dsum + 1e-16f);
  __syncthreads();

  float acc = 0.f;
  for (int jj = wid; jj < deg; jj += 4) {
    int s = (jj < CAP1) ? scol[jj] : col[beg + jj];
    float v = h1[(size_t)s * 64 + lane];
    float w;
    if (jj < CAP1) {
      w = wt[jj];
    } else {
      float e = as[s] + adv;
      e = (e > 0.f) ? e : NEG_SLOPE * e;
      w = __expf(e - m);
    }
    acc = fmaf(w, v, acc);
  }
  accbuf[wid][lane] = acc;
  __syncthreads();

  if (tid < 64) {
    float o = accbuf[0][tid] + accbuf[1][tid] + accbuf[2][tid] + accbuf[3][tid];
    out[(size_t)n * 64 + tid] = o * inv + bias[tid];
  }
}

// ------------------------- launch -------------------------

extern "C" void kernel_launch(void* const* d_in, const int* in_sizes, int n_in,
                              void* d_out, int out_size, void* d_ws, size_t ws_size,
                              hipStream_t stream) {
  const float* x        = (const float*)d_in[0];
  const int*   eidx     = (const int*)d_in[1];
  const float* W0       = (const float*)d_in[2];
  const float* att_src0 = (const float*)d_in[3];
  const float* att_dst0 = (const float*)d_in[4];
  const float* b0       = (const float*)d_in[5];
  const float* W1       = (const float*)d_in[6];
  const float* att_src1 = (const float*)d_in[7];
  const float* att_dst1 = (const float*)d_in[8];
  const float* b1       = (const float*)d_in[9];
  float* out = (float*)d_out;

  const int F_IN = 256, HID = 256, H = 4, C = 64;
  const int N = in_sizes[0] / F_IN;       // 50000
  const int E = in_sizes[1] / 2;          // 800000
  const int ET = E + N;                   // with self-loops

  const int* src = eidx;
  const int* dst = eidx + E;

  // workspace layout
  char* w = (char*)d_ws;
  auto take = [&](size_t bytes) {
    char* p = w;
    w += (bytes + 255) & ~(size_t)255;
    return p;
  };
  float*    h0      = (float*)take((size_t)N * HID * 4);
  unsigned* h0b     = (unsigned*)take((size_t)N * (HID / 2) * 4);
  float*    x1      = (float*)take((size_t)N * HID * 4);
  float*    h1      = (float*)take((size_t)N * C * 4);
  float*    as0     = (float*)take((size_t)N * H * 4);
  float*    ad0     = (float*)take((size_t)N * H * 4);
  float*    as1     = (float*)take((size_t)N * 4);
  float*    ad1     = (float*)take((size_t)N * 4);
  int*      row_off = (int*)take((size_t)(N + 1) * 4);
  int*      cursor  = (int*)take((size_t)N * 4);
  int*      counts  = (int*)take((size_t)N * 4);
  int*      col     = (int*)take((size_t)ET * 4);

  // --- CSR build ---
  hipMemsetAsync(counts, 0, (size_t)N * 4, stream);
  {
    int blocks = (ET + 255) / 256;
    gat_count_kernel<<<blocks, 256, 0, stream>>>(dst, E, N, counts);
    gat_scan_kernel<<<1, 1024, 0, stream>>>(counts, row_off, cursor, N);
    gat_fill_kernel<<<blocks, 256, 0, stream>>>(src, dst, E, N, cursor, col);
  }

  // --- layer 0 ---
  {
    dim3 grid(HID / 64, (N + 63) / 64);
    gat_gemm_f32<<<grid, 256, 0, stream>>>(x, W0, h0, h0b, N, F_IN, HID);
  }
  {
    int blocks = (N * H + 3) / 4;
    gat_alpha_kernel<<<blocks, 256, 0, stream>>>(h0, att_src0, att_dst0, as0, ad0, N, H);
  }
  gat_agg0_kernel<<<N, 256, 0, stream>>>(h0b, as0, ad0, row_off, col, b0, x1, N);

  // --- layer 1 ---
  {
    dim3 grid(C / 64, (N + 63) / 64);
    gat_gemm_f32<<<grid, 256, 0, stream>>>(x1, W1, h1, nullptr, N, HID, C);
  }
  {
    int blocks = (N * 1 + 3) / 4;
    gat_alpha_kernel<<<blocks, 256, 0, stream>>>(h1, att_src1, att_dst1, as1, ad1, N, 1);
  }
  gat_agg1_kernel<<<N, 256, 0, stream>>>(h1, as1, ad1, row_off, col, b1, out, N);
}

// Round 8
// 429.735 us; speedup vs baseline: 1.4519x; 1.2133x over previous
//
#include <hip/hip_runtime.h>
#include <hip/hip_bf16.h>
#include <math.h>

// ---------------------------------------------------------------------------
// GAT 2-layer forward. bf16 MFMA GEMMs + bf16 gather tables, fp32 softmax.
// R1: agg kernels restructured (edge-parallel waves, LDS weight cache).
// R2: col[] staged in LDS; bf16-packed h0 gather (FETCH 435->216MB, 159->115us).
// R5: both GEMMs -> bf16 MFMA (16x16x32), x/W pre-converted, GEMM0 emits only
//     bf16 h0b, agg0 emits bf16 x1b, alpha0 reads bf16. fp32 h1 kept for agg1.
// R6/R7: resubmits (bench infra failures on dead container, no data).
// ---------------------------------------------------------------------------

#define NEG_SLOPE 0.2f
#define CAP0 128
#define CAP1 128

typedef __attribute__((ext_vector_type(8))) short bf16x8;
typedef __attribute__((ext_vector_type(4))) float f32x4;

static __device__ __forceinline__ unsigned f2bf_rne(float f) {
  unsigned u = __float_as_uint(f);
  return (u + 0x7fffu + ((u >> 16) & 1u)) >> 16;  // round-to-nearest-even
}
static __device__ __forceinline__ float bf2f(unsigned u16) {
  return __uint_as_float(u16 << 16);
}

// ------------------------- converts -------------------------

// fp32 -> bf16, 8 elems/thread (count must be divisible by 8: N*256 ok)
__global__ void gat_cvt_bf16(const float* __restrict__ in,
                             ushort* __restrict__ out, int n8) {
  int i = blockIdx.x * blockDim.x + threadIdx.x;
  if (i >= n8) return;
  float4 a = *(const float4*)&in[(size_t)i * 8];
  float4 b = *(const float4*)&in[(size_t)i * 8 + 4];
  uint4 o;
  o.x = f2bf_rne(a.x) | (f2bf_rne(a.y) << 16);
  o.y = f2bf_rne(a.z) | (f2bf_rne(a.w) << 16);
  o.z = f2bf_rne(b.x) | (f2bf_rne(b.y) << 16);
  o.w = f2bf_rne(b.z) | (f2bf_rne(b.w) << 16);
  *(uint4*)&out[(size_t)i * 8] = o;
}

// W[K][Nw] fp32 -> Wt[Nw][K] bf16 (tiny weights; simple per-element)
__global__ void gat_cvtT_bf16(const float* __restrict__ W,
                              ushort* __restrict__ Wt, int K, int Nw) {
  int i = blockIdx.x * blockDim.x + threadIdx.x;
  if (i >= K * Nw) return;
  int n = i / K, k = i - n * K;
  Wt[i] = (ushort)f2bf_rne(W[(size_t)k * Nw + n]);
}

// ------------------------- CSR build -------------------------

__global__ void gat_count_kernel(const int* __restrict__ dst, int E, int N,
                                 int* __restrict__ counts) {
  int i = blockIdx.x * blockDim.x + threadIdx.x;
  int ET = E + N;
  if (i >= ET) return;
  int d = (i < E) ? dst[i] : (i - E);
  atomicAdd(&counts[d], 1);
}

__global__ __launch_bounds__(1024) void gat_scan_kernel(
    const int* __restrict__ counts, int* __restrict__ row_off,
    int* __restrict__ cursor, int n) {
  __shared__ int wsum[16];
  __shared__ int s_carry;
  int tid = threadIdx.x;
  int lane = tid & 63;
  int wid = tid >> 6;
  if (tid == 0) s_carry = 0;
  __syncthreads();
  const int TILE = 4096;
  for (int base = 0; base < n; base += TILE) {
    int idx = base + tid * 4;
    int4 v = {0, 0, 0, 0};
    if (idx + 3 < n) {
      v = *(const int4*)&counts[idx];
    } else {
      if (idx + 0 < n) v.x = counts[idx + 0];
      if (idx + 1 < n) v.y = counts[idx + 1];
      if (idx + 2 < n) v.z = counts[idx + 2];
      if (idx + 3 < n) v.w = counts[idx + 3];
    }
    int t0 = v.x, t1 = t0 + v.y, t2 = t1 + v.z, t3 = t2 + v.w;
    int x = t3;
    #pragma unroll
    for (int off = 1; off < 64; off <<= 1) {
      int y = __shfl_up(x, off, 64);
      if (lane >= off) x += y;
    }
    if (lane == 63) wsum[wid] = x;
    __syncthreads();
    if (tid < 16) {
      int s = wsum[tid];
      #pragma unroll
      for (int off = 1; off < 16; off <<= 1) {
        int y = __shfl_up(s, off, 16);
        if (tid >= off) s += y;
      }
      wsum[tid] = s;
    }
    __syncthreads();
    int carry = s_carry;
    int excl_wave = (wid > 0) ? wsum[wid - 1] : 0;
    int b = carry + excl_wave + (x - t3);
    if (idx + 0 < n) { row_off[idx + 0] = b;      cursor[idx + 0] = b;      }
    if (idx + 1 < n) { row_off[idx + 1] = b + t0; cursor[idx + 1] = b + t0; }
    if (idx + 2 < n) { row_off[idx + 2] = b + t1; cursor[idx + 2] = b + t1; }
    if (idx + 3 < n) { row_off[idx + 3] = b + t2; cursor[idx + 3] = b + t2; }
    __syncthreads();
    if (tid == 1023) s_carry = b + t3;  // carry + tile total
    __syncthreads();
  }
  if (threadIdx.x == 0) row_off[n] = s_carry;
}

__global__ void gat_fill_kernel(const int* __restrict__ src,
                                const int* __restrict__ dst, int E, int N,
                                int* __restrict__ cursor, int* __restrict__ col) {
  int i = blockIdx.x * blockDim.x + threadIdx.x;
  int ET = E + N;
  if (i >= ET) return;
  int s, d;
  if (i < E) { s = src[i]; d = dst[i]; }
  else       { s = d = i - E; }
  int pos = atomicAdd(&cursor[d], 1);
  col[pos] = s;
}

// ------------------------- GEMM (bf16 MFMA) -------------------------
// C[M,N] = A[M,K] @ Bt[N,K]^T. BM=128, BK=32, 256 thr = 4 waves.
// Per-wave WM x WN via 16x16x32 MFMA. LDS rows padded to 40 ushorts
// (80B stride -> balanced 4-bank spans, conflict-free b128 reads).

template <int BN, int WM, int WN, bool WRITE_F32, bool WRITE_BF16>
__global__ __launch_bounds__(256) void gat_gemm_bf16(
    const ushort* __restrict__ A, const ushort* __restrict__ Bt,
    float* __restrict__ C, ushort* __restrict__ Cb, int M, int K, int N) {
  constexpr int BM = 128, BK = 32;
  constexpr int MR = WM / 16, NR = WN / 16;
  constexpr int WCOLS = BN / WN;
  __shared__ __align__(16) ushort Al[BM][40];
  __shared__ __align__(16) ushort Bl[BN][40];
  int tid = threadIdx.x;
  int lane = tid & 63, wid = tid >> 6;
  int wrow = (wid / WCOLS) * WM, wcol = (wid % WCOLS) * WN;
  int brow = blockIdx.x * BM, bcol = blockIdx.y * BN;
  int r0 = tid >> 2, seg = tid & 3;  // staging: 64 rows x 4 x 16B per pass
  int kg = lane >> 4, rl = lane & 15;
  f32x4 acc[MR][NR] = {};
  for (int k0 = 0; k0 < K; k0 += BK) {
    #pragma unroll
    for (int h = 0; h < BM / 64; ++h) {
      int row = r0 + h * 64;
      int ar = brow + row;
      uint4 v = make_uint4(0u, 0u, 0u, 0u);
      if (ar < M) v = *(const uint4*)&A[(size_t)ar * K + k0 + seg * 8];
      *(uint4*)&Al[row][seg * 8] = v;
    }
    #pragma unroll
    for (int h = 0; h < BN / 64; ++h) {
      int row = r0 + h * 64;
      uint4 v = *(const uint4*)&Bt[(size_t)(bcol + row) * K + k0 + seg * 8];
      *(uint4*)&Bl[row][seg * 8] = v;
    }
    __syncthreads();
    bf16x8 af[MR], bfr[NR];
    #pragma unroll
    for (int m = 0; m < MR; ++m)
      af[m] = *(const bf16x8*)&Al[wrow + m * 16 + rl][kg * 8];
    #pragma unroll
    for (int n = 0; n < NR; ++n)
      bfr[n] = *(const bf16x8*)&Bl[wcol + n * 16 + rl][kg * 8];
    #pragma unroll
    for (int m = 0; m < MR; ++m)
      #pragma unroll
      for (int n = 0; n < NR; ++n)
        acc[m][n] = __builtin_amdgcn_mfma_f32_16x16x32_bf16(
            af[m], bfr[n], acc[m][n], 0, 0, 0);
    __syncthreads();
  }
  // epilogue: D row = (lane>>4)*4 + j, col = lane&15
  int orow = kg * 4;
  #pragma unroll
  for (int m = 0; m < MR; ++m) {
    #pragma unroll
    for (int j = 0; j < 4; ++j) {
      int r = brow + wrow + m * 16 + orow + j;
      if (r < M) {
        #pragma unroll
        for (int n = 0; n < NR; ++n) {
          int c = bcol + wcol + n * 16 + rl;
          float v = acc[m][n][j];
          if constexpr (WRITE_F32) C[(size_t)r * N + c] = v;
          if constexpr (WRITE_BF16) Cb[(size_t)r * N + c] = (ushort)f2bf_rne(v);
        }
      }
    }
  }
}

// ------------------------- alpha kernels -------------------------

// bf16 input (layer 0): one wave per (node, head)
__global__ __launch_bounds__(256) void gat_alpha_b_kernel(
    const ushort* __restrict__ hb, const float* __restrict__ a_src,
    const float* __restrict__ a_dst, float* __restrict__ as_out,
    float* __restrict__ ad_out, int N, int H) {
  int lane = threadIdx.x & 63;
  int wid = threadIdx.x >> 6;
  int g = blockIdx.x * 4 + wid;  // = n*H + h
  if (g >= N * H) return;
  int hh = g % H;
  float v = bf2f(hb[(size_t)g * 64 + lane]);
  float s = v * a_src[hh * 64 + lane];
  float d = v * a_dst[hh * 64 + lane];
  #pragma unroll
  for (int off = 32; off; off >>= 1) {
    s += __shfl_xor(s, off, 64);
    d += __shfl_xor(d, off, 64);
  }
  if (lane == 0) {
    as_out[g] = s;
    ad_out[g] = d;
  }
}

// fp32 input (layer 1)
__global__ __launch_bounds__(256) void gat_alpha_kernel(
    const float* __restrict__ h, const float* __restrict__ a_src,
    const float* __restrict__ a_dst, float* __restrict__ as_out,
    float* __restrict__ ad_out, int N, int H) {
  int lane = threadIdx.x & 63;
  int wid = threadIdx.x >> 6;
  int g = blockIdx.x * 4 + wid;
  if (g >= N * H) return;
  int hh = g % H;
  float v = h[(size_t)g * 64 + lane];
  float s = v * a_src[hh * 64 + lane];
  float d = v * a_dst[hh * 64 + lane];
  #pragma unroll
  for (int off = 32; off; off >>= 1) {
    s += __shfl_xor(s, off, 64);
    d += __shfl_xor(d, off, 64);
  }
  if (lane == 0) {
    as_out[g] = s;
    ad_out[g] = d;
  }
}

// ------------------------- layer-0 aggregation -------------------------
// one block (256 thr) per node. col[] staged in LDS; weights in LDS;
// waves split edges (mod 4); bf16 row gather (8B/lane); bf16 x1 output.

__global__ __launch_bounds__(256) void gat_agg0_kernel(
    const unsigned* __restrict__ h0b, const float* __restrict__ as,
    const float* __restrict__ ad, const int* __restrict__ row_off,
    const int* __restrict__ col, const float* __restrict__ bias,
    ushort* __restrict__ x1b, int N) {
  __shared__ int scol[CAP0];
  __shared__ float wt[4][CAP0];
  __shared__ float accbuf[4][256];
  __shared__ float sm_m[4];
  __shared__ float sm_inv[4];
  int n = blockIdx.x;
  int tid = threadIdx.x;
  int lane = tid & 63;
  int wid = tid >> 6;
  int beg = row_off[n];
  int end = row_off[n + 1];
  int deg = end - beg;
  int degc = deg < CAP0 ? deg : CAP0;
  for (int jj = tid; jj < degc; jj += 256) scol[jj] = col[beg + jj];
  __syncthreads();

  // pass 1: e (stashed) + per-head max (wave wid owns head wid)
  float adv = ad[n * 4 + wid];
  float m = -INFINITY;
  for (int jj = lane; jj < deg; jj += 64) {
    int s = (jj < CAP0) ? scol[jj] : col[beg + jj];
    float e = as[s * 4 + wid] + adv;
    e = (e > 0.f) ? e : NEG_SLOPE * e;
    if (jj < CAP0) wt[wid][jj] = e;
    m = fmaxf(m, e);
  }
  #pragma unroll
  for (int off = 32; off; off >>= 1) m = fmaxf(m, __shfl_xor(m, off, 64));

  // pass 2: w = exp(e-m) (stashed) + denom
  float dsum = 0.f;
  for (int jj = lane; jj < deg; jj += 64) {
    float e;
    if (jj < CAP0) {
      e = wt[wid][jj];
    } else {
      int s = col[beg + jj];
      e = as[s * 4 + wid] + adv;
      e = (e > 0.f) ? e : NEG_SLOPE * e;
    }
    float w = __expf(e - m);
    if (jj < CAP0) wt[wid][jj] = w;
    dsum += w;
  }
  #pragma unroll
  for (int off = 32; off; off >>= 1) dsum += __shfl_xor(dsum, off, 64);
  if (lane == 0) {
    sm_m[wid] = m;
    sm_inv[wid] = 1.f / (dsum + 1e-16f);
  }
  __syncthreads();

  // pass 3: edge-parallel weighted gather (bf16 rows, 8B/lane)
  int q = lane >> 4;
  float4 acc = make_float4(0.f, 0.f, 0.f, 0.f);
  for (int jj = wid; jj < deg; jj += 4) {
    int s = (jj < CAP0) ? scol[jj] : col[beg + jj];
    uint2 v = *(const uint2*)(h0b + (size_t)s * 128 + lane * 2);
    float w;
    if (jj < CAP0) {
      w = wt[q][jj];
    } else {
      float e = as[s * 4 + q] + ad[n * 4 + q];
      e = (e > 0.f) ? e : NEG_SLOPE * e;
      w = __expf(e - sm_m[q]);
    }
    float v0 = __uint_as_float(v.x << 16);
    float v1 = __uint_as_float(v.x & 0xffff0000u);
    float v2 = __uint_as_float(v.y << 16);
    float v3 = __uint_as_float(v.y & 0xffff0000u);
    acc.x = fmaf(w, v0, acc.x);
    acc.y = fmaf(w, v1, acc.y);
    acc.z = fmaf(w, v2, acc.z);
    acc.w = fmaf(w, v3, acc.w);
  }
  *(float4*)&accbuf[wid][lane * 4] = acc;
  __syncthreads();

  float o = accbuf[0][tid] + accbuf[1][tid] + accbuf[2][tid] + accbuf[3][tid];
  o = o * sm_inv[tid >> 6] + bias[tid];
  o = (o > 0.f) ? o : (__expf(o) - 1.f);  // ELU
  x1b[(size_t)n * 256 + tid] = (ushort)f2bf_rne(o);
}

// ------------------------- layer-1 aggregation -------------------------

__global__ __launch_bounds__(256) void gat_agg1_kernel(
    const float* __restrict__ h1, const float* __restrict__ as,
    const float* __restrict__ ad, const int* __restrict__ row_off,
    const int* __restrict__ col, const float* __restrict__ bias,
    float* __restrict__ out, int N) {
  __shared__ int scol[CAP1];
  __shared__ float wt[CAP1];
  __shared__ float accbuf[4][64];
  int n = blockIdx.x;
  int tid = threadIdx.x;
  int lane = tid & 63;
  int wid = tid >> 6;
  int beg = row_off[n];
  int end = row_off[n + 1];
  int deg = end - beg;
  int degc = deg < CAP1 ? deg : CAP1;
  for (int jj = tid; jj < degc; jj += 256) scol[jj] = col[beg + jj];
  __syncthreads();
  float adv = ad[n];

  float m = -INFINITY;
  for (int jj = lane; jj < deg; jj += 64) {
    int s = (jj < CAP1) ? scol[jj] : col[beg + jj];
    float e = as[s] + adv;
    e = (e > 0.f) ? e : NEG_SLOPE * e;
    m = fmaxf(m, e);
  }
  #pragma unroll
  for (int off = 32; off; off >>= 1) m = fmaxf(m, __shfl_xor(m, off, 64));

  float dsum = 0.f;
  for (int jj = lane; jj < deg; jj += 64) {
    int s = (jj < CAP1) ? scol[jj] : col[beg + jj];
    float e = as[s] + adv;
    e = (e > 0.f) ? e : NEG_SLOPE * e;
    float w = __expf(e - m);
    dsum += w;
    if (wid == 0 && jj < CAP1) wt[jj] = w;
  }
  #pragma unroll
  for (int off = 32; off; off >>= 1) dsum += __shfl_xor(dsum, off, 64);
  float inv = 1.f / (dsum + 1e-16f);
  __syncthreads();

  float acc = 0.f;
  for (int jj = wid; jj < deg; jj += 4) {
    int s = (jj < CAP1) ? scol[jj] : col[beg + jj];
    float v = h1[(size_t)s * 64 + lane];
    float w;
    if (jj < CAP1) {
      w = wt[jj];
    } else {
      float e = as[s] + adv;
      e = (e > 0.f) ? e : NEG_SLOPE * e;
      w = __expf(e - m);
    }
    acc = fmaf(w, v, acc);
  }
  accbuf[wid][lane] = acc;
  __syncthreads();

  if (tid < 64) {
    float o = accbuf[0][tid] + accbuf[1][tid] + accbuf[2][tid] + accbuf[3][tid];
    out[(size_t)n * 64 + tid] = o * inv + bias[tid];
  }
}

// ------------------------- launch -------------------------

extern "C" void kernel_launch(void* const* d_in, const int* in_sizes, int n_in,
                              void* d_out, int out_size, void* d_ws, size_t ws_size,
                              hipStream_t stream) {
  const float* x        = (const float*)d_in[0];
  const int*   eidx     = (const int*)d_in[1];
  const float* W0       = (const float*)d_in[2];
  const float* att_src0 = (const float*)d_in[3];
  const float* att_dst0 = (const float*)d_in[4];
  const float* b0       = (const float*)d_in[5];
  const float* W1       = (const float*)d_in[6];
  const float* att_src1 = (const float*)d_in[7];
  const float* att_dst1 = (const float*)d_in[8];
  const float* b1       = (const float*)d_in[9];
  float* out = (float*)d_out;

  const int F_IN = 256, HID = 256, H = 4, C = 64;
  const int N = in_sizes[0] / F_IN;       // 50000
  const int E = in_sizes[1] / 2;          // 800000
  const int ET = E + N;                   // with self-loops

  const int* src = eidx;
  const int* dst = eidx + E;

  // workspace layout
  char* w = (char*)d_ws;
  auto take = [&](size_t bytes) {
    char* p = w;
    w += (bytes + 255) & ~(size_t)255;
    return p;
  };
  ushort* xb      = (ushort*)take((size_t)N * F_IN * 2);
  ushort* W0t     = (ushort*)take((size_t)F_IN * HID * 2);
  ushort* W1t     = (ushort*)take((size_t)HID * C * 2);
  ushort* h0b     = (ushort*)take((size_t)N * HID * 2);
  ushort* x1b     = (ushort*)take((size_t)N * HID * 2);
  float*  h1      = (float*)take((size_t)N * C * 4);
  float*  as0     = (float*)take((size_t)N * H * 4);
  float*  ad0     = (float*)take((size_t)N * H * 4);
  float*  as1     = (float*)take((size_t)N * 4);
  float*  ad1     = (float*)take((size_t)N * 4);
  int*    row_off = (int*)take((size_t)(N + 1) * 4);
  int*    cursor  = (int*)take((size_t)N * 4);
  int*    counts  = (int*)take((size_t)N * 4);
  int*    col     = (int*)take((size_t)ET * 4);

  // --- converts ---
  {
    int n8 = N * F_IN / 8;
    gat_cvt_bf16<<<(n8 + 255) / 256, 256, 0, stream>>>(x, xb, n8);
    gat_cvtT_bf16<<<(F_IN * HID + 255) / 256, 256, 0, stream>>>(W0, W0t, F_IN, HID);
    gat_cvtT_bf16<<<(HID * C + 255) / 256, 256, 0, stream>>>(W1, W1t, HID, C);
  }

  // --- CSR build ---
  hipMemsetAsync(counts, 0, (size_t)N * 4, stream);
  {
    int blocks = (ET + 255) / 256;
    gat_count_kernel<<<blocks, 256, 0, stream>>>(dst, E, N, counts);
    gat_scan_kernel<<<1, 1024, 0, stream>>>(counts, row_off, cursor, N);
    gat_fill_kernel<<<blocks, 256, 0, stream>>>(src, dst, E, N, cursor, col);
  }

  // --- layer 0 ---
  {
    dim3 grid((N + 127) / 128, HID / 128);
    gat_gemm_bf16<128, 64, 64, false, true>
        <<<grid, 256, 0, stream>>>(xb, W0t, nullptr, h0b, N, F_IN, HID);
  }
  {
    int blocks = (N * H + 3) / 4;
    gat_alpha_b_kernel<<<blocks, 256, 0, stream>>>(h0b, att_src0, att_dst0,
                                                   as0, ad0, N, H);
  }
  gat_agg0_kernel<<<N, 256, 0, stream>>>((const unsigned*)h0b, as0, ad0,
                                         row_off, col, b0, x1b, N);

  // --- layer 1 ---
  {
    dim3 grid((N + 127) / 128, C / 64);
    gat_gemm_bf16<64, 32, 64, true, false>
        <<<grid, 256, 0, stream>>>(x1b, W1t, h1, nullptr, N, HID, C);
  }
  {
    int blocks = (N * 1 + 3) / 4;
    gat_alpha_kernel<<<blocks, 256, 0, stream>>>(h1, att_src1, att_dst1,
                                                 as1, ad1, N, 1);
  }
  gat_agg1_kernel<<<N, 256, 0, stream>>>(h1, as1, ad1, row_off, col, b1, out, N);
}

// Round 9
// 371.995 us; speedup vs baseline: 1.6773x; 1.1552x over previous
//
#include <hip/hip_runtime.h>
#include <hip/hip_bf16.h>
#include <math.h>

// ---------------------------------------------------------------------------
// GAT 2-layer forward. bf16 MFMA GEMMs + bf16 gather tables, fp32 softmax.
// R1: agg kernels restructured (edge-parallel waves, LDS weight cache).
// R2: col[] staged in LDS; bf16-packed h0 gather (FETCH 435->216MB, 159->115us).
// R5: both GEMMs -> bf16 MFMA; GEMM0 emits bf16 h0b; agg0 emits bf16 x1b.
//     (521 -> 430us, absmax 0.0039)
// R8: agg0/agg1 -> wave-per-node, ZERO barriers: packed-lane softmax
//     (4 heads x 16 slots, 4-step shuffles), per-wave LDS weights,
//     serial-edge gather with full MLP. (was: 3-barrier block-per-node)
// ---------------------------------------------------------------------------

#define NEG_SLOPE 0.2f
#define CAP0 128
#define CAP1 128

typedef __attribute__((ext_vector_type(8))) short bf16x8;
typedef __attribute__((ext_vector_type(4))) float f32x4;

static __device__ __forceinline__ unsigned f2bf_rne(float f) {
  unsigned u = __float_as_uint(f);
  return (u + 0x7fffu + ((u >> 16) & 1u)) >> 16;  // round-to-nearest-even
}
static __device__ __forceinline__ float bf2f(unsigned u16) {
  return __uint_as_float(u16 << 16);
}

// ------------------------- converts -------------------------

__global__ void gat_cvt_bf16(const float* __restrict__ in,
                             ushort* __restrict__ out, int n8) {
  int i = blockIdx.x * blockDim.x + threadIdx.x;
  if (i >= n8) return;
  float4 a = *(const float4*)&in[(size_t)i * 8];
  float4 b = *(const float4*)&in[(size_t)i * 8 + 4];
  uint4 o;
  o.x = f2bf_rne(a.x) | (f2bf_rne(a.y) << 16);
  o.y = f2bf_rne(a.z) | (f2bf_rne(a.w) << 16);
  o.z = f2bf_rne(b.x) | (f2bf_rne(b.y) << 16);
  o.w = f2bf_rne(b.z) | (f2bf_rne(b.w) << 16);
  *(uint4*)&out[(size_t)i * 8] = o;
}

__global__ void gat_cvtT_bf16(const float* __restrict__ W,
                              ushort* __restrict__ Wt, int K, int Nw) {
  int i = blockIdx.x * blockDim.x + threadIdx.x;
  if (i >= K * Nw) return;
  int n = i / K, k = i - n * K;
  Wt[i] = (ushort)f2bf_rne(W[(size_t)k * Nw + n]);
}

// ------------------------- CSR build -------------------------

__global__ void gat_count_kernel(const int* __restrict__ dst, int E, int N,
                                 int* __restrict__ counts) {
  int i = blockIdx.x * blockDim.x + threadIdx.x;
  int ET = E + N;
  if (i >= ET) return;
  int d = (i < E) ? dst[i] : (i - E);
  atomicAdd(&counts[d], 1);
}

__global__ __launch_bounds__(1024) void gat_scan_kernel(
    const int* __restrict__ counts, int* __restrict__ row_off,
    int* __restrict__ cursor, int n) {
  __shared__ int wsum[16];
  __shared__ int s_carry;
  int tid = threadIdx.x;
  int lane = tid & 63;
  int wid = tid >> 6;
  if (tid == 0) s_carry = 0;
  __syncthreads();
  const int TILE = 4096;
  for (int base = 0; base < n; base += TILE) {
    int idx = base + tid * 4;
    int4 v = {0, 0, 0, 0};
    if (idx + 3 < n) {
      v = *(const int4*)&counts[idx];
    } else {
      if (idx + 0 < n) v.x = counts[idx + 0];
      if (idx + 1 < n) v.y = counts[idx + 1];
      if (idx + 2 < n) v.z = counts[idx + 2];
      if (idx + 3 < n) v.w = counts[idx + 3];
    }
    int t0 = v.x, t1 = t0 + v.y, t2 = t1 + v.z, t3 = t2 + v.w;
    int x = t3;
    #pragma unroll
    for (int off = 1; off < 64; off <<= 1) {
      int y = __shfl_up(x, off, 64);
      if (lane >= off) x += y;
    }
    if (lane == 63) wsum[wid] = x;
    __syncthreads();
    if (tid < 16) {
      int s = wsum[tid];
      #pragma unroll
      for (int off = 1; off < 16; off <<= 1) {
        int y = __shfl_up(s, off, 16);
        if (tid >= off) s += y;
      }
      wsum[tid] = s;
    }
    __syncthreads();
    int carry = s_carry;
    int excl_wave = (wid > 0) ? wsum[wid - 1] : 0;
    int b = carry + excl_wave + (x - t3);
    if (idx + 0 < n) { row_off[idx + 0] = b;      cursor[idx + 0] = b;      }
    if (idx + 1 < n) { row_off[idx + 1] = b + t0; cursor[idx + 1] = b + t0; }
    if (idx + 2 < n) { row_off[idx + 2] = b + t1; cursor[idx + 2] = b + t1; }
    if (idx + 3 < n) { row_off[idx + 3] = b + t2; cursor[idx + 3] = b + t2; }
    __syncthreads();
    if (tid == 1023) s_carry = b + t3;  // carry + tile total
    __syncthreads();
  }
  if (threadIdx.x == 0) row_off[n] = s_carry;
}

__global__ void gat_fill_kernel(const int* __restrict__ src,
                                const int* __restrict__ dst, int E, int N,
                                int* __restrict__ cursor, int* __restrict__ col) {
  int i = blockIdx.x * blockDim.x + threadIdx.x;
  int ET = E + N;
  if (i >= ET) return;
  int s, d;
  if (i < E) { s = src[i]; d = dst[i]; }
  else       { s = d = i - E; }
  int pos = atomicAdd(&cursor[d], 1);
  col[pos] = s;
}

// ------------------------- GEMM (bf16 MFMA) -------------------------
// C[M,N] = A[M,K] @ Bt[N,K]^T. BM=128, BK=32, 256 thr = 4 waves.

template <int BN, int WM, int WN, bool WRITE_F32, bool WRITE_BF16>
__global__ __launch_bounds__(256) void gat_gemm_bf16(
    const ushort* __restrict__ A, const ushort* __restrict__ Bt,
    float* __restrict__ C, ushort* __restrict__ Cb, int M, int K, int N) {
  constexpr int BM = 128, BK = 32;
  constexpr int MR = WM / 16, NR = WN / 16;
  constexpr int WCOLS = BN / WN;
  __shared__ __align__(16) ushort Al[BM][40];
  __shared__ __align__(16) ushort Bl[BN][40];
  int tid = threadIdx.x;
  int lane = tid & 63, wid = tid >> 6;
  int wrow = (wid / WCOLS) * WM, wcol = (wid % WCOLS) * WN;
  int brow = blockIdx.x * BM, bcol = blockIdx.y * BN;
  int r0 = tid >> 2, seg = tid & 3;
  int kg = lane >> 4, rl = lane & 15;
  f32x4 acc[MR][NR] = {};
  for (int k0 = 0; k0 < K; k0 += BK) {
    #pragma unroll
    for (int h = 0; h < BM / 64; ++h) {
      int row = r0 + h * 64;
      int ar = brow + row;
      uint4 v = make_uint4(0u, 0u, 0u, 0u);
      if (ar < M) v = *(const uint4*)&A[(size_t)ar * K + k0 + seg * 8];
      *(uint4*)&Al[row][seg * 8] = v;
    }
    #pragma unroll
    for (int h = 0; h < BN / 64; ++h) {
      int row = r0 + h * 64;
      uint4 v = *(const uint4*)&Bt[(size_t)(bcol + row) * K + k0 + seg * 8];
      *(uint4*)&Bl[row][seg * 8] = v;
    }
    __syncthreads();
    bf16x8 af[MR], bfr[NR];
    #pragma unroll
    for (int m = 0; m < MR; ++m)
      af[m] = *(const bf16x8*)&Al[wrow + m * 16 + rl][kg * 8];
    #pragma unroll
    for (int n = 0; n < NR; ++n)
      bfr[n] = *(const bf16x8*)&Bl[wcol + n * 16 + rl][kg * 8];
    #pragma unroll
    for (int m = 0; m < MR; ++m)
      #pragma unroll
      for (int n = 0; n < NR; ++n)
        acc[m][n] = __builtin_amdgcn_mfma_f32_16x16x32_bf16(
            af[m], bfr[n], acc[m][n], 0, 0, 0);
    __syncthreads();
  }
  int orow = kg * 4;
  #pragma unroll
  for (int m = 0; m < MR; ++m) {
    #pragma unroll
    for (int j = 0; j < 4; ++j) {
      int r = brow + wrow + m * 16 + orow + j;
      if (r < M) {
        #pragma unroll
        for (int n = 0; n < NR; ++n) {
          int c = bcol + wcol + n * 16 + rl;
          float v = acc[m][n][j];
          if constexpr (WRITE_F32) C[(size_t)r * N + c] = v;
          if constexpr (WRITE_BF16) Cb[(size_t)r * N + c] = (ushort)f2bf_rne(v);
        }
      }
    }
  }
}

// ------------------------- alpha kernels -------------------------

__global__ __launch_bounds__(256) void gat_alpha_b_kernel(
    const ushort* __restrict__ hb, const float* __restrict__ a_src,
    const float* __restrict__ a_dst, float* __restrict__ as_out,
    float* __restrict__ ad_out, int N, int H) {
  int lane = threadIdx.x & 63;
  int wid = threadIdx.x >> 6;
  int g = blockIdx.x * 4 + wid;  // = n*H + h
  if (g >= N * H) return;
  int hh = g % H;
  float v = bf2f(hb[(size_t)g * 64 + lane]);
  float s = v * a_src[hh * 64 + lane];
  float d = v * a_dst[hh * 64 + lane];
  #pragma unroll
  for (int off = 32; off; off >>= 1) {
    s += __shfl_xor(s, off, 64);
    d += __shfl_xor(d, off, 64);
  }
  if (lane == 0) {
    as_out[g] = s;
    ad_out[g] = d;
  }
}

__global__ __launch_bounds__(256) void gat_alpha_kernel(
    const float* __restrict__ h, const float* __restrict__ a_src,
    const float* __restrict__ a_dst, float* __restrict__ as_out,
    float* __restrict__ ad_out, int N, int H) {
  int lane = threadIdx.x & 63;
  int wid = threadIdx.x >> 6;
  int g = blockIdx.x * 4 + wid;
  if (g >= N * H) return;
  int hh = g % H;
  float v = h[(size_t)g * 64 + lane];
  float s = v * a_src[hh * 64 + lane];
  float d = v * a_dst[hh * 64 + lane];
  #pragma unroll
  for (int off = 32; off; off >>= 1) {
    s += __shfl_xor(s, off, 64);
    d += __shfl_xor(d, off, 64);
  }
  if (lane == 0) {
    as_out[g] = s;
    ad_out[g] = d;
  }
}

// ------------------------- layer-0 aggregation -------------------------
// WAVE per node, zero barriers. Softmax: lane=(q=lane>>4 head, slot=lane&15),
// 4-step 16-lane shuffle reduces for all 4 heads at once; weights in this
// wave's LDS slice. Gather: serial edges, 8B/lane bf16, all loads in flight.

__global__ __launch_bounds__(256) void gat_agg0_kernel(
    const unsigned* __restrict__ h0b, const float* __restrict__ as,
    const float* __restrict__ ad, const int* __restrict__ row_off,
    const int* __restrict__ col, const float* __restrict__ bias,
    ushort* __restrict__ x1b, int N) {
  __shared__ int scol[4][CAP0];
  __shared__ float wt[4][4][CAP0];
  int lane = threadIdx.x & 63;
  int wid = threadIdx.x >> 6;
  int n = blockIdx.x * 4 + wid;
  if (n >= N) return;  // whole wave exits; no barriers in this kernel
  int beg = row_off[n];
  int deg = row_off[n + 1] - beg;
  int degc = deg < CAP0 ? deg : CAP0;
  for (int jj = lane; jj < degc; jj += 64) scol[wid][jj] = col[beg + jj];

  int q = lane >> 4, slot = lane & 15;
  float adv = ad[n * 4 + q];

  // pass 1: e (stashed) + per-head max via 16-lane reduce
  float m = -INFINITY;
  for (int jj = slot; jj < deg; jj += 16) {
    int s = (jj < CAP0) ? scol[wid][jj] : col[beg + jj];
    float e = as[s * 4 + q] + adv;
    e = (e > 0.f) ? e : NEG_SLOPE * e;
    if (jj < CAP0) wt[wid][q][jj] = e;
    m = fmaxf(m, e);
  }
  #pragma unroll
  for (int off = 8; off; off >>= 1) m = fmaxf(m, __shfl_xor(m, off, 64));

  // pass 2: w = exp(e-m) (stashed) + denom
  float dsum = 0.f;
  for (int jj = slot; jj < deg; jj += 16) {
    float e;
    if (jj < CAP0) {
      e = wt[wid][q][jj];
    } else {
      int s = col[beg + jj];
      e = as[s * 4 + q] + adv;
      e = (e > 0.f) ? e : NEG_SLOPE * e;
    }
    float w = __expf(e - m);
    if (jj < CAP0) wt[wid][q][jj] = w;
    dsum += w;
  }
  #pragma unroll
  for (int off = 8; off; off >>= 1) dsum += __shfl_xor(dsum, off, 64);
  float inv = 1.f / (dsum + 1e-16f);

  // gather: serial over edges, independent 8B loads (4 bf16 ch per lane)
  float4 acc = make_float4(0.f, 0.f, 0.f, 0.f);
  for (int jj = 0; jj < deg; ++jj) {
    int s = (jj < CAP0) ? scol[wid][jj] : col[beg + jj];
    s = __builtin_amdgcn_readfirstlane(s);  // wave-uniform -> SGPR base
    uint2 v = *(const uint2*)(h0b + (size_t)s * 128 + lane * 2);
    float w;
    if (jj < CAP0) {
      w = wt[wid][q][jj];
    } else {
      float e = as[s * 4 + q] + adv;
      e = (e > 0.f) ? e : NEG_SLOPE * e;
      w = __expf(e - m);
    }
    acc.x = fmaf(w, __uint_as_float(v.x << 16), acc.x);
    acc.y = fmaf(w, __uint_as_float(v.x & 0xffff0000u), acc.y);
    acc.z = fmaf(w, __uint_as_float(v.y << 16), acc.z);
    acc.w = fmaf(w, __uint_as_float(v.y & 0xffff0000u), acc.w);
  }

  // epilogue: scale, bias, ELU, pack bf16
  int c0 = lane * 4;
  float4 bv = *(const float4*)&bias[c0];
  float o0 = acc.x * inv + bv.x;
  float o1 = acc.y * inv + bv.y;
  float o2 = acc.z * inv + bv.z;
  float o3 = acc.w * inv + bv.w;
  o0 = (o0 > 0.f) ? o0 : (__expf(o0) - 1.f);
  o1 = (o1 > 0.f) ? o1 : (__expf(o1) - 1.f);
  o2 = (o2 > 0.f) ? o2 : (__expf(o2) - 1.f);
  o3 = (o3 > 0.f) ? o3 : (__expf(o3) - 1.f);
  uint2 p;
  p.x = f2bf_rne(o0) | (f2bf_rne(o1) << 16);
  p.y = f2bf_rne(o2) | (f2bf_rne(o3) << 16);
  *(uint2*)&x1b[(size_t)n * 256 + c0] = p;
}

// ------------------------- layer-1 aggregation -------------------------
// WAVE per node, zero barriers. H=1: 64-lane edge reduce; fp32 gather.

__global__ __launch_bounds__(256) void gat_agg1_kernel(
    const float* __restrict__ h1, const float* __restrict__ as,
    const float* __restrict__ ad, const int* __restrict__ row_off,
    const int* __restrict__ col, const float* __restrict__ bias,
    float* __restrict__ out, int N) {
  __shared__ int scol[4][CAP1];
  __shared__ float wt[4][CAP1];
  int lane = threadIdx.x & 63;
  int wid = threadIdx.x >> 6;
  int n = blockIdx.x * 4 + wid;
  if (n >= N) return;
  int beg = row_off[n];
  int deg = row_off[n + 1] - beg;
  int degc = deg < CAP1 ? deg : CAP1;
  for (int jj = lane; jj < degc; jj += 64) scol[wid][jj] = col[beg + jj];
  float adv = ad[n];

  float m = -INFINITY;
  for (int jj = lane; jj < deg; jj += 64) {
    int s = (jj < CAP1) ? scol[wid][jj] : col[beg + jj];
    float e = as[s] + adv;
    e = (e > 0.f) ? e : NEG_SLOPE * e;
    if (jj < CAP1) wt[wid][jj] = e;
    m = fmaxf(m, e);
  }
  #pragma unroll
  for (int off = 32; off; off >>= 1) m = fmaxf(m, __shfl_xor(m, off, 64));

  float dsum = 0.f;
  for (int jj = lane; jj < deg; jj += 64) {
    float e;
    if (jj < CAP1) {
      e = wt[wid][jj];
    } else {
      int s = col[beg + jj];
      e = as[s] + adv;
      e = (e > 0.f) ? e : NEG_SLOPE * e;
    }
    float w = __expf(e - m);
    if (jj < CAP1) wt[wid][jj] = w;
    dsum += w;
  }
  #pragma unroll
  for (int off = 32; off; off >>= 1) dsum += __shfl_xor(dsum, off, 64);
  float inv = 1.f / (dsum + 1e-16f);

  float acc = 0.f;
  for (int jj = 0; jj < deg; ++jj) {
    int s = (jj < CAP1) ? scol[wid][jj] : col[beg + jj];
    s = __builtin_amdgcn_readfirstlane(s);
    float v = h1[(size_t)s * 64 + lane];
    float w;
    if (jj < CAP1) {
      w = wt[wid][jj];
    } else {
      float e = as[s] + adv;
      e = (e > 0.f) ? e : NEG_SLOPE * e;
      w = __expf(e - m);
    }
    acc = fmaf(w, v, acc);
  }
  out[(size_t)n * 64 + lane] = acc * inv + bias[lane];
}

// ------------------------- launch -------------------------

extern "C" void kernel_launch(void* const* d_in, const int* in_sizes, int n_in,
                              void* d_out, int out_size, void* d_ws, size_t ws_size,
                              hipStream_t stream) {
  const float* x        = (const float*)d_in[0];
  const int*   eidx     = (const int*)d_in[1];
  const float* W0       = (const float*)d_in[2];
  const float* att_src0 = (const float*)d_in[3];
  const float* att_dst0 = (const float*)d_in[4];
  const float* b0       = (const float*)d_in[5];
  const float* W1       = (const float*)d_in[6];
  const float* att_src1 = (const float*)d_in[7];
  const float* att_dst1 = (const float*)d_in[8];
  const float* b1       = (const float*)d_in[9];
  float* out = (float*)d_out;

  const int F_IN = 256, HID = 256, H = 4, C = 64;
  const int N = in_sizes[0] / F_IN;       // 50000
  const int E = in_sizes[1] / 2;          // 800000
  const int ET = E + N;                   // with self-loops

  const int* src = eidx;
  const int* dst = eidx + E;

  // workspace layout
  char* w = (char*)d_ws;
  auto take = [&](size_t bytes) {
    char* p = w;
    w += (bytes + 255) & ~(size_t)255;
    return p;
  };
  ushort* xb      = (ushort*)take((size_t)N * F_IN * 2);
  ushort* W0t     = (ushort*)take((size_t)F_IN * HID * 2);
  ushort* W1t     = (ushort*)take((size_t)HID * C * 2);
  ushort* h0b     = (ushort*)take((size_t)N * HID * 2);
  ushort* x1b     = (ushort*)take((size_t)N * HID * 2);
  float*  h1      = (float*)take((size_t)N * C * 4);
  float*  as0     = (float*)take((size_t)N * H * 4);
  float*  ad0     = (float*)take((size_t)N * H * 4);
  float*  as1     = (float*)take((size_t)N * 4);
  float*  ad1     = (float*)take((size_t)N * 4);
  int*    row_off = (int*)take((size_t)(N + 1) * 4);
  int*    cursor  = (int*)take((size_t)N * 4);
  int*    counts  = (int*)take((size_t)N * 4);
  int*    col     = (int*)take((size_t)ET * 4);

  // --- converts ---
  {
    int n8 = N * F_IN / 8;
    gat_cvt_bf16<<<(n8 + 255) / 256, 256, 0, stream>>>(x, xb, n8);
    gat_cvtT_bf16<<<(F_IN * HID + 255) / 256, 256, 0, stream>>>(W0, W0t, F_IN, HID);
    gat_cvtT_bf16<<<(HID * C + 255) / 256, 256, 0, stream>>>(W1, W1t, HID, C);
  }

  // --- CSR build ---
  hipMemsetAsync(counts, 0, (size_t)N * 4, stream);
  {
    int blocks = (ET + 255) / 256;
    gat_count_kernel<<<blocks, 256, 0, stream>>>(dst, E, N, counts);
    gat_scan_kernel<<<1, 1024, 0, stream>>>(counts, row_off, cursor, N);
    gat_fill_kernel<<<blocks, 256, 0, stream>>>(src, dst, E, N, cursor, col);
  }

  // --- layer 0 ---
  {
    dim3 grid((N + 127) / 128, HID / 128);
    gat_gemm_bf16<128, 64, 64, false, true>
        <<<grid, 256, 0, stream>>>(xb, W0t, nullptr, h0b, N, F_IN, HID);
  }
  {
    int blocks = (N * H + 3) / 4;
    gat_alpha_b_kernel<<<blocks, 256, 0, stream>>>(h0b, att_src0, att_dst0,
                                                   as0, ad0, N, H);
  }
  gat_agg0_kernel<<<(N + 3) / 4, 256, 0, stream>>>((const unsigned*)h0b, as0,
                                                   ad0, row_off, col, b0, x1b, N);

  // --- layer 1 ---
  {
    dim3 grid((N + 127) / 128, C / 64);
    gat_gemm_bf16<64, 32, 64, true, false>
        <<<grid, 256, 0, stream>>>(x1b, W1t, h1, nullptr, N, HID, C);
  }
  {
    int blocks = (N * 1 + 3) / 4;
    gat_alpha_kernel<<<blocks, 256, 0, stream>>>(h1, att_src1, att_dst1,
                                                 as1, ad1, N, 1);
  }
  gat_agg1_kernel<<<(N + 3) / 4, 256, 0, stream>>>(h1, as1, ad1, row_off, col,
                                                   b1, out, N);
}

// Round 10
// 325.003 us; speedup vs baseline: 1.9198x; 1.1446x over previous
//
#include <hip/hip_runtime.h>
#include <hip/hip_bf16.h>
#include <math.h>

// ---------------------------------------------------------------------------
// GAT 2-layer forward. bf16 MFMA GEMMs + bf16 gather tables, fp32 softmax.
// R2: col[] staged in LDS; bf16-packed h0 gather (FETCH 435->216MB).
// R5: both GEMMs -> bf16 MFMA. (521 -> 430us, absmax 0.0039)
// R8: agg0/agg1 -> wave-per-node, zero barriers (430 -> 372us; agg0 86us,
//     loop-carried latency-bound: ~1 load in flight).
// R9: 4-deep software-pipelined gather (4 row loads in flight before use);
//     wt re-layout [wid][jj][q] kills 4-way LDS write conflict.
// ---------------------------------------------------------------------------

#define NEG_SLOPE 0.2f
#define CAP0 128
#define CAP1 128

typedef __attribute__((ext_vector_type(8))) short bf16x8;
typedef __attribute__((ext_vector_type(4))) float f32x4;

static __device__ __forceinline__ unsigned f2bf_rne(float f) {
  unsigned u = __float_as_uint(f);
  return (u + 0x7fffu + ((u >> 16) & 1u)) >> 16;  // round-to-nearest-even
}
static __device__ __forceinline__ float bf2f(unsigned u16) {
  return __uint_as_float(u16 << 16);
}

// ------------------------- converts -------------------------

__global__ void gat_cvt_bf16(const float* __restrict__ in,
                             ushort* __restrict__ out, int n8) {
  int i = blockIdx.x * blockDim.x + threadIdx.x;
  if (i >= n8) return;
  float4 a = *(const float4*)&in[(size_t)i * 8];
  float4 b = *(const float4*)&in[(size_t)i * 8 + 4];
  uint4 o;
  o.x = f2bf_rne(a.x) | (f2bf_rne(a.y) << 16);
  o.y = f2bf_rne(a.z) | (f2bf_rne(a.w) << 16);
  o.z = f2bf_rne(b.x) | (f2bf_rne(b.y) << 16);
  o.w = f2bf_rne(b.z) | (f2bf_rne(b.w) << 16);
  *(uint4*)&out[(size_t)i * 8] = o;
}

__global__ void gat_cvtT_bf16(const float* __restrict__ W,
                              ushort* __restrict__ Wt, int K, int Nw) {
  int i = blockIdx.x * blockDim.x + threadIdx.x;
  if (i >= K * Nw) return;
  int n = i / K, k = i - n * K;
  Wt[i] = (ushort)f2bf_rne(W[(size_t)k * Nw + n]);
}

// ------------------------- CSR build -------------------------

__global__ void gat_count_kernel(const int* __restrict__ dst, int E, int N,
                                 int* __restrict__ counts) {
  int i = blockIdx.x * blockDim.x + threadIdx.x;
  int ET = E + N;
  if (i >= ET) return;
  int d = (i < E) ? dst[i] : (i - E);
  atomicAdd(&counts[d], 1);
}

__global__ __launch_bounds__(1024) void gat_scan_kernel(
    const int* __restrict__ counts, int* __restrict__ row_off,
    int* __restrict__ cursor, int n) {
  __shared__ int wsum[16];
  __shared__ int s_carry;
  int tid = threadIdx.x;
  int lane = tid & 63;
  int wid = tid >> 6;
  if (tid == 0) s_carry = 0;
  __syncthreads();
  const int TILE = 4096;
  for (int base = 0; base < n; base += TILE) {
    int idx = base + tid * 4;
    int4 v = {0, 0, 0, 0};
    if (idx + 3 < n) {
      v = *(const int4*)&counts[idx];
    } else {
      if (idx + 0 < n) v.x = counts[idx + 0];
      if (idx + 1 < n) v.y = counts[idx + 1];
      if (idx + 2 < n) v.z = counts[idx + 2];
      if (idx + 3 < n) v.w = counts[idx + 3];
    }
    int t0 = v.x, t1 = t0 + v.y, t2 = t1 + v.z, t3 = t2 + v.w;
    int x = t3;
    #pragma unroll
    for (int off = 1; off < 64; off <<= 1) {
      int y = __shfl_up(x, off, 64);
      if (lane >= off) x += y;
    }
    if (lane == 63) wsum[wid] = x;
    __syncthreads();
    if (tid < 16) {
      int s = wsum[tid];
      #pragma unroll
      for (int off = 1; off < 16; off <<= 1) {
        int y = __shfl_up(s, off, 16);
        if (tid >= off) s += y;
      }
      wsum[tid] = s;
    }
    __syncthreads();
    int carry = s_carry;
    int excl_wave = (wid > 0) ? wsum[wid - 1] : 0;
    int b = carry + excl_wave + (x - t3);
    if (idx + 0 < n) { row_off[idx + 0] = b;      cursor[idx + 0] = b;      }
    if (idx + 1 < n) { row_off[idx + 1] = b + t0; cursor[idx + 1] = b + t0; }
    if (idx + 2 < n) { row_off[idx + 2] = b + t1; cursor[idx + 2] = b + t1; }
    if (idx + 3 < n) { row_off[idx + 3] = b + t2; cursor[idx + 3] = b + t2; }
    __syncthreads();
    if (tid == 1023) s_carry = b + t3;  // carry + tile total
    __syncthreads();
  }
  if (threadIdx.x == 0) row_off[n] = s_carry;
}

__global__ void gat_fill_kernel(const int* __restrict__ src,
                                const int* __restrict__ dst, int E, int N,
                                int* __restrict__ cursor, int* __restrict__ col) {
  int i = blockIdx.x * blockDim.x + threadIdx.x;
  int ET = E + N;
  if (i >= ET) return;
  int s, d;
  if (i < E) { s = src[i]; d = dst[i]; }
  else       { s = d = i - E; }
  int pos = atomicAdd(&cursor[d], 1);
  col[pos] = s;
}

// ------------------------- GEMM (bf16 MFMA) -------------------------
// C[M,N] = A[M,K] @ Bt[N,K]^T. BM=128, BK=32, 256 thr = 4 waves.

template <int BN, int WM, int WN, bool WRITE_F32, bool WRITE_BF16>
__global__ __launch_bounds__(256) void gat_gemm_bf16(
    const ushort* __restrict__ A, const ushort* __restrict__ Bt,
    float* __restrict__ C, ushort* __restrict__ Cb, int M, int K, int N) {
  constexpr int BM = 128, BK = 32;
  constexpr int MR = WM / 16, NR = WN / 16;
  constexpr int WCOLS = BN / WN;
  __shared__ __align__(16) ushort Al[BM][40];
  __shared__ __align__(16) ushort Bl[BN][40];
  int tid = threadIdx.x;
  int lane = tid & 63, wid = tid >> 6;
  int wrow = (wid / WCOLS) * WM, wcol = (wid % WCOLS) * WN;
  int brow = blockIdx.x * BM, bcol = blockIdx.y * BN;
  int r0 = tid >> 2, seg = tid & 3;
  int kg = lane >> 4, rl = lane & 15;
  f32x4 acc[MR][NR] = {};
  for (int k0 = 0; k0 < K; k0 += BK) {
    #pragma unroll
    for (int h = 0; h < BM / 64; ++h) {
      int row = r0 + h * 64;
      int ar = brow + row;
      uint4 v = make_uint4(0u, 0u, 0u, 0u);
      if (ar < M) v = *(const uint4*)&A[(size_t)ar * K + k0 + seg * 8];
      *(uint4*)&Al[row][seg * 8] = v;
    }
    #pragma unroll
    for (int h = 0; h < BN / 64; ++h) {
      int row = r0 + h * 64;
      uint4 v = *(const uint4*)&Bt[(size_t)(bcol + row) * K + k0 + seg * 8];
      *(uint4*)&Bl[row][seg * 8] = v;
    }
    __syncthreads();
    bf16x8 af[MR], bfr[NR];
    #pragma unroll
    for (int m = 0; m < MR; ++m)
      af[m] = *(const bf16x8*)&Al[wrow + m * 16 + rl][kg * 8];
    #pragma unroll
    for (int n = 0; n < NR; ++n)
      bfr[n] = *(const bf16x8*)&Bl[wcol + n * 16 + rl][kg * 8];
    #pragma unroll
    for (int m = 0; m < MR; ++m)
      #pragma unroll
      for (int n = 0; n < NR; ++n)
        acc[m][n] = __builtin_amdgcn_mfma_f32_16x16x32_bf16(
            af[m], bfr[n], acc[m][n], 0, 0, 0);
    __syncthreads();
  }
  int orow = kg * 4;
  #pragma unroll
  for (int m = 0; m < MR; ++m) {
    #pragma unroll
    for (int j = 0; j < 4; ++j) {
      int r = brow + wrow + m * 16 + orow + j;
      if (r < M) {
        #pragma unroll
        for (int n = 0; n < NR; ++n) {
          int c = bcol + wcol + n * 16 + rl;
          float v = acc[m][n][j];
          if constexpr (WRITE_F32) C[(size_t)r * N + c] = v;
          if constexpr (WRITE_BF16) Cb[(size_t)r * N + c] = (ushort)f2bf_rne(v);
        }
      }
    }
  }
}

// ------------------------- alpha kernels -------------------------

__global__ __launch_bounds__(256) void gat_alpha_b_kernel(
    const ushort* __restrict__ hb, const float* __restrict__ a_src,
    const float* __restrict__ a_dst, float* __restrict__ as_out,
    float* __restrict__ ad_out, int N, int H) {
  int lane = threadIdx.x & 63;
  int wid = threadIdx.x >> 6;
  int g = blockIdx.x * 4 + wid;  // = n*H + h
  if (g >= N * H) return;
  int hh = g % H;
  float v = bf2f(hb[(size_t)g * 64 + lane]);
  float s = v * a_src[hh * 64 + lane];
  float d = v * a_dst[hh * 64 + lane];
  #pragma unroll
  for (int off = 32; off; off >>= 1) {
    s += __shfl_xor(s, off, 64);
    d += __shfl_xor(d, off, 64);
  }
  if (lane == 0) {
    as_out[g] = s;
    ad_out[g] = d;
  }
}

__global__ __launch_bounds__(256) void gat_alpha_kernel(
    const float* __restrict__ h, const float* __restrict__ a_src,
    const float* __restrict__ a_dst, float* __restrict__ as_out,
    float* __restrict__ ad_out, int N, int H) {
  int lane = threadIdx.x & 63;
  int wid = threadIdx.x >> 6;
  int g = blockIdx.x * 4 + wid;
  if (g >= N * H) return;
  int hh = g % H;
  float v = h[(size_t)g * 64 + lane];
  float s = v * a_src[hh * 64 + lane];
  float d = v * a_dst[hh * 64 + lane];
  #pragma unroll
  for (int off = 32; off; off >>= 1) {
    s += __shfl_xor(s, off, 64);
    d += __shfl_xor(d, off, 64);
  }
  if (lane == 0) {
    as_out[g] = s;
    ad_out[g] = d;
  }
}

// ------------------------- layer-0 aggregation -------------------------
// WAVE per node, zero barriers. Softmax: lane=(q=lane>>4, slot=lane&15).
// Gather: 4-deep software pipeline (4 independent row loads in flight).

__global__ __launch_bounds__(256) void gat_agg0_kernel(
    const unsigned* __restrict__ h0b, const float* __restrict__ as,
    const float* __restrict__ ad, const int* __restrict__ row_off,
    const int* __restrict__ col, const float* __restrict__ bias,
    ushort* __restrict__ x1b, int N) {
  __shared__ int scol[4][CAP0];
  __shared__ float wt[4][CAP0][4];  // [wid][edge][head] — conflict-free
  int lane = threadIdx.x & 63;
  int wid = threadIdx.x >> 6;
  int n = blockIdx.x * 4 + wid;
  if (n >= N) return;  // whole wave exits; no barriers in this kernel
  int beg = row_off[n];
  int deg = row_off[n + 1] - beg;
  int degc = deg < CAP0 ? deg : CAP0;
  for (int jj = lane; jj < degc; jj += 64) scol[wid][jj] = col[beg + jj];

  int q = lane >> 4, slot = lane & 15;
  float adv = ad[n * 4 + q];

  // pass 1: e (stashed) + per-head max via 16-lane reduce
  float m = -INFINITY;
  for (int jj = slot; jj < deg; jj += 16) {
    int s = (jj < CAP0) ? scol[wid][jj] : col[beg + jj];
    float e = as[s * 4 + q] + adv;
    e = (e > 0.f) ? e : NEG_SLOPE * e;
    if (jj < CAP0) wt[wid][jj][q] = e;
    m = fmaxf(m, e);
  }
  #pragma unroll
  for (int off = 8; off; off >>= 1) m = fmaxf(m, __shfl_xor(m, off, 64));

  // pass 2: w = exp(e-m) (stashed) + denom
  float dsum = 0.f;
  for (int jj = slot; jj < deg; jj += 16) {
    float e;
    if (jj < CAP0) {
      e = wt[wid][jj][q];
    } else {
      int s = col[beg + jj];
      e = as[s * 4 + q] + adv;
      e = (e > 0.f) ? e : NEG_SLOPE * e;
    }
    float w = __expf(e - m);
    if (jj < CAP0) wt[wid][jj][q] = w;
    dsum += w;
  }
  #pragma unroll
  for (int off = 8; off; off >>= 1) dsum += __shfl_xor(dsum, off, 64);
  float inv = 1.f / (dsum + 1e-16f);

  // gather: 4-deep pipelined (fast path deg<=CAP0: no fallback branches)
  float4 acc = make_float4(0.f, 0.f, 0.f, 0.f);
  int c2 = lane * 2;
  if (deg <= CAP0) {
    int jj = 0;
    for (; jj + 4 <= deg; jj += 4) {
      int s0 = __builtin_amdgcn_readfirstlane(scol[wid][jj + 0]);
      int s1 = __builtin_amdgcn_readfirstlane(scol[wid][jj + 1]);
      int s2 = __builtin_amdgcn_readfirstlane(scol[wid][jj + 2]);
      int s3 = __builtin_amdgcn_readfirstlane(scol[wid][jj + 3]);
      uint2 v0 = *(const uint2*)(h0b + (size_t)s0 * 128 + c2);
      uint2 v1 = *(const uint2*)(h0b + (size_t)s1 * 128 + c2);
      uint2 v2 = *(const uint2*)(h0b + (size_t)s2 * 128 + c2);
      uint2 v3 = *(const uint2*)(h0b + (size_t)s3 * 128 + c2);
      float w0 = wt[wid][jj + 0][q];
      float w1 = wt[wid][jj + 1][q];
      float w2 = wt[wid][jj + 2][q];
      float w3 = wt[wid][jj + 3][q];
      acc.x = fmaf(w0, __uint_as_float(v0.x << 16), acc.x);
      acc.y = fmaf(w0, __uint_as_float(v0.x & 0xffff0000u), acc.y);
      acc.z = fmaf(w0, __uint_as_float(v0.y << 16), acc.z);
      acc.w = fmaf(w0, __uint_as_float(v0.y & 0xffff0000u), acc.w);
      acc.x = fmaf(w1, __uint_as_float(v1.x << 16), acc.x);
      acc.y = fmaf(w1, __uint_as_float(v1.x & 0xffff0000u), acc.y);
      acc.z = fmaf(w1, __uint_as_float(v1.y << 16), acc.z);
      acc.w = fmaf(w1, __uint_as_float(v1.y & 0xffff0000u), acc.w);
      acc.x = fmaf(w2, __uint_as_float(v2.x << 16), acc.x);
      acc.y = fmaf(w2, __uint_as_float(v2.x & 0xffff0000u), acc.y);
      acc.z = fmaf(w2, __uint_as_float(v2.y << 16), acc.z);
      acc.w = fmaf(w2, __uint_as_float(v2.y & 0xffff0000u), acc.w);
      acc.x = fmaf(w3, __uint_as_float(v3.x << 16), acc.x);
      acc.y = fmaf(w3, __uint_as_float(v3.x & 0xffff0000u), acc.y);
      acc.z = fmaf(w3, __uint_as_float(v3.y << 16), acc.z);
      acc.w = fmaf(w3, __uint_as_float(v3.y & 0xffff0000u), acc.w);
    }
    for (; jj < deg; ++jj) {
      int s = __builtin_amdgcn_readfirstlane(scol[wid][jj]);
      uint2 v = *(const uint2*)(h0b + (size_t)s * 128 + c2);
      float w = wt[wid][jj][q];
      acc.x = fmaf(w, __uint_as_float(v.x << 16), acc.x);
      acc.y = fmaf(w, __uint_as_float(v.x & 0xffff0000u), acc.y);
      acc.z = fmaf(w, __uint_as_float(v.y << 16), acc.z);
      acc.w = fmaf(w, __uint_as_float(v.y & 0xffff0000u), acc.w);
    }
  } else {  // huge-degree fallback (practically never)
    for (int jj = 0; jj < deg; ++jj) {
      int s = (jj < CAP0) ? scol[wid][jj] : col[beg + jj];
      s = __builtin_amdgcn_readfirstlane(s);
      uint2 v = *(const uint2*)(h0b + (size_t)s * 128 + c2);
      float w;
      if (jj < CAP0) {
        w = wt[wid][jj][q];
      } else {
        float e = as[s * 4 + q] + adv;
        e = (e > 0.f) ? e : NEG_SLOPE * e;
        w = __expf(e - m);
      }
      acc.x = fmaf(w, __uint_as_float(v.x << 16), acc.x);
      acc.y = fmaf(w, __uint_as_float(v.x & 0xffff0000u), acc.y);
      acc.z = fmaf(w, __uint_as_float(v.y << 16), acc.z);
      acc.w = fmaf(w, __uint_as_float(v.y & 0xffff0000u), acc.w);
    }
  }

  // epilogue: scale, bias, ELU, pack bf16
  int c0 = lane * 4;
  float4 bv = *(const float4*)&bias[c0];
  float o0 = acc.x * inv + bv.x;
  float o1 = acc.y * inv + bv.y;
  float o2 = acc.z * inv + bv.z;
  float o3 = acc.w * inv + bv.w;
  o0 = (o0 > 0.f) ? o0 : (__expf(o0) - 1.f);
  o1 = (o1 > 0.f) ? o1 : (__expf(o1) - 1.f);
  o2 = (o2 > 0.f) ? o2 : (__expf(o2) - 1.f);
  o3 = (o3 > 0.f) ? o3 : (__expf(o3) - 1.f);
  uint2 p;
  p.x = f2bf_rne(o0) | (f2bf_rne(o1) << 16);
  p.y = f2bf_rne(o2) | (f2bf_rne(o3) << 16);
  *(uint2*)&x1b[(size_t)n * 256 + c0] = p;
}

// ------------------------- layer-1 aggregation -------------------------
// WAVE per node, zero barriers. H=1; 4-deep pipelined fp32 gather.

__global__ __launch_bounds__(256) void gat_agg1_kernel(
    const float* __restrict__ h1, const float* __restrict__ as,
    const float* __restrict__ ad, const int* __restrict__ row_off,
    const int* __restrict__ col, const float* __restrict__ bias,
    float* __restrict__ out, int N) {
  __shared__ int scol[4][CAP1];
  __shared__ float wt[4][CAP1];
  int lane = threadIdx.x & 63;
  int wid = threadIdx.x >> 6;
  int n = blockIdx.x * 4 + wid;
  if (n >= N) return;
  int beg = row_off[n];
  int deg = row_off[n + 1] - beg;
  int degc = deg < CAP1 ? deg : CAP1;
  for (int jj = lane; jj < degc; jj += 64) scol[wid][jj] = col[beg + jj];
  float adv = ad[n];

  float m = -INFINITY;
  for (int jj = lane; jj < deg; jj += 64) {
    int s = (jj < CAP1) ? scol[wid][jj] : col[beg + jj];
    float e = as[s] + adv;
    e = (e > 0.f) ? e : NEG_SLOPE * e;
    if (jj < CAP1) wt[wid][jj] = e;
    m = fmaxf(m, e);
  }
  #pragma unroll
  for (int off = 32; off; off >>= 1) m = fmaxf(m, __shfl_xor(m, off, 64));

  float dsum = 0.f;
  for (int jj = lane; jj < deg; jj += 64) {
    float e;
    if (jj < CAP1) {
      e = wt[wid][jj];
    } else {
      int s = col[beg + jj];
      e = as[s] + adv;
      e = (e > 0.f) ? e : NEG_SLOPE * e;
    }
    float w = __expf(e - m);
    if (jj < CAP1) wt[wid][jj] = w;
    dsum += w;
  }
  #pragma unroll
  for (int off = 32; off; off >>= 1) dsum += __shfl_xor(dsum, off, 64);
  float inv = 1.f / (dsum + 1e-16f);

  float acc = 0.f;
  if (deg <= CAP1) {
    int jj = 0;
    for (; jj + 4 <= deg; jj += 4) {
      int s0 = __builtin_amdgcn_readfirstlane(scol[wid][jj + 0]);
      int s1 = __builtin_amdgcn_readfirstlane(scol[wid][jj + 1]);
      int s2 = __builtin_amdgcn_readfirstlane(scol[wid][jj + 2]);
      int s3 = __builtin_amdgcn_readfirstlane(scol[wid][jj + 3]);
      float v0 = h1[(size_t)s0 * 64 + lane];
      float v1 = h1[(size_t)s1 * 64 + lane];
      float v2 = h1[(size_t)s2 * 64 + lane];
      float v3 = h1[(size_t)s3 * 64 + lane];
      acc = fmaf(wt[wid][jj + 0], v0, acc);
      acc = fmaf(wt[wid][jj + 1], v1, acc);
      acc = fmaf(wt[wid][jj + 2], v2, acc);
      acc = fmaf(wt[wid][jj + 3], v3, acc);
    }
    for (; jj < deg; ++jj) {
      int s = __builtin_amdgcn_readfirstlane(scol[wid][jj]);
      acc = fmaf(wt[wid][jj], h1[(size_t)s * 64 + lane], acc);
    }
  } else {
    for (int jj = 0; jj < deg; ++jj) {
      int s = (jj < CAP1) ? scol[wid][jj] : col[beg + jj];
      s = __builtin_amdgcn_readfirstlane(s);
      float v = h1[(size_t)s * 64 + lane];
      float w;
      if (jj < CAP1) {
        w = wt[wid][jj];
      } else {
        float e = as[s] + adv;
        e = (e > 0.f) ? e : NEG_SLOPE * e;
        w = __expf(e - m);
      }
      acc = fmaf(w, v, acc);
    }
  }
  out[(size_t)n * 64 + lane] = acc * inv + bias[lane];
}

// ------------------------- launch -------------------------

extern "C" void kernel_launch(void* const* d_in, const int* in_sizes, int n_in,
                              void* d_out, int out_size, void* d_ws, size_t ws_size,
                              hipStream_t stream) {
  const float* x        = (const float*)d_in[0];
  const int*   eidx     = (const int*)d_in[1];
  const float* W0       = (const float*)d_in[2];
  const float* att_src0 = (const float*)d_in[3];
  const float* att_dst0 = (const float*)d_in[4];
  const float* b0       = (const float*)d_in[5];
  const float* W1       = (const float*)d_in[6];
  const float* att_src1 = (const float*)d_in[7];
  const float* att_dst1 = (const float*)d_in[8];
  const float* b1       = (const float*)d_in[9];
  float* out = (float*)d_out;

  const int F_IN = 256, HID = 256, H = 4, C = 64;
  const int N = in_sizes[0] / F_IN;       // 50000
  const int E = in_sizes[1] / 2;          // 800000
  const int ET = E + N;                   // with self-loops

  const int* src = eidx;
  const int* dst = eidx + E;

  // workspace layout
  char* w = (char*)d_ws;
  auto take = [&](size_t bytes) {
    char* p = w;
    w += (bytes + 255) & ~(size_t)255;
    return p;
  };
  ushort* xb      = (ushort*)take((size_t)N * F_IN * 2);
  ushort* W0t     = (ushort*)take((size_t)F_IN * HID * 2);
  ushort* W1t     = (ushort*)take((size_t)HID * C * 2);
  ushort* h0b     = (ushort*)take((size_t)N * HID * 2);
  ushort* x1b     = (ushort*)take((size_t)N * HID * 2);
  float*  h1      = (float*)take((size_t)N * C * 4);
  float*  as0     = (float*)take((size_t)N * H * 4);
  float*  ad0     = (float*)take((size_t)N * H * 4);
  float*  as1     = (float*)take((size_t)N * 4);
  float*  ad1     = (float*)take((size_t)N * 4);
  int*    row_off = (int*)take((size_t)(N + 1) * 4);
  int*    cursor  = (int*)take((size_t)N * 4);
  int*    counts  = (int*)take((size_t)N * 4);
  int*    col     = (int*)take((size_t)ET * 4);

  // --- converts ---
  {
    int n8 = N * F_IN / 8;
    gat_cvt_bf16<<<(n8 + 255) / 256, 256, 0, stream>>>(x, xb, n8);
    gat_cvtT_bf16<<<(F_IN * HID + 255) / 256, 256, 0, stream>>>(W0, W0t, F_IN, HID);
    gat_cvtT_bf16<<<(HID * C + 255) / 256, 256, 0, stream>>>(W1, W1t, HID, C);
  }

  // --- CSR build ---
  hipMemsetAsync(counts, 0, (size_t)N * 4, stream);
  {
    int blocks = (ET + 255) / 256;
    gat_count_kernel<<<blocks, 256, 0, stream>>>(dst, E, N, counts);
    gat_scan_kernel<<<1, 1024, 0, stream>>>(counts, row_off, cursor, N);
    gat_fill_kernel<<<blocks, 256, 0, stream>>>(src, dst, E, N, cursor, col);
  }

  // --- layer 0 ---
  {
    dim3 grid((N + 127) / 128, HID / 128);
    gat_gemm_bf16<128, 64, 64, false, true>
        <<<grid, 256, 0, stream>>>(xb, W0t, nullptr, h0b, N, F_IN, HID);
  }
  {
    int blocks = (N * H + 3) / 4;
    gat_alpha_b_kernel<<<blocks, 256, 0, stream>>>(h0b, att_src0, att_dst0,
                                                   as0, ad0, N, H);
  }
  gat_agg0_kernel<<<(N + 3) / 4, 256, 0, stream>>>((const unsigned*)h0b, as0,
                                                   ad0, row_off, col, b0, x1b, N);

  // --- layer 1 ---
  {
    dim3 grid((N + 127) / 128, C / 64);
    gat_gemm_bf16<64, 32, 64, true, false>
        <<<grid, 256, 0, stream>>>(x1b, W1t, h1, nullptr, N, HID, C);
  }
  {
    int blocks = (N * 1 + 3) / 4;
    gat_alpha_kernel<<<blocks, 256, 0, stream>>>(h1, att_src1, att_dst1,
                                                 as1, ad1, N, 1);
  }
  gat_agg1_kernel<<<(N + 3) / 4, 256, 0, stream>>>(h1, as1, ad1, row_off, col,
                                                   b1, out, N);
}

// Round 12
// 280.685 us; speedup vs baseline: 2.2230x; 1.1579x over previous
//
#include <hip/hip_runtime.h>
#include <hip/hip_bf16.h>
#include <math.h>

// ---------------------------------------------------------------------------
// GAT 2-layer forward. bf16 MFMA GEMMs + bf16 gather tables, fp32 softmax.
// R5: both GEMMs -> bf16 MFMA. R8: wave-per-node zero-barrier agg.
// R9: 4-deep pipelined gather, wt[wid][jj][q] layout (agg0 86.6->66us).
// R10: alpha fused into GEMM epilogues; GEMM1 -> bf16 h1b; 8-deep pipelines.
// R11: fix macro-hygiene compile error (FMA4 'w' param captured acc.w) ->
//      inline fma4() function. No functional change vs R10 intent.
// ---------------------------------------------------------------------------

#define NEG_SLOPE 0.2f
#define CAP0 128
#define CAP1 128

typedef __attribute__((ext_vector_type(8))) short bf16x8;
typedef __attribute__((ext_vector_type(4))) float f32x4;

static __device__ __forceinline__ unsigned f2bf_rne(float f) {
  unsigned u = __float_as_uint(f);
  return (u + 0x7fffu + ((u >> 16) & 1u)) >> 16;  // round-to-nearest-even
}
static __device__ __forceinline__ float bf2f(unsigned u16) {
  return __uint_as_float(u16 << 16);
}
static __device__ __forceinline__ void fma4(float4& acc, float w, uint2 v) {
  acc.x = fmaf(w, __uint_as_float(v.x << 16), acc.x);
  acc.y = fmaf(w, __uint_as_float(v.x & 0xffff0000u), acc.y);
  acc.z = fmaf(w, __uint_as_float(v.y << 16), acc.z);
  acc.w = fmaf(w, __uint_as_float(v.y & 0xffff0000u), acc.w);
}

// ------------------------- converts -------------------------

__global__ void gat_cvt_bf16(const float* __restrict__ in,
                             ushort* __restrict__ out, int n8) {
  int i = blockIdx.x * blockDim.x + threadIdx.x;
  if (i >= n8) return;
  float4 a = *(const float4*)&in[(size_t)i * 8];
  float4 b = *(const float4*)&in[(size_t)i * 8 + 4];
  uint4 o;
  o.x = f2bf_rne(a.x) | (f2bf_rne(a.y) << 16);
  o.y = f2bf_rne(a.z) | (f2bf_rne(a.w) << 16);
  o.z = f2bf_rne(b.x) | (f2bf_rne(b.y) << 16);
  o.w = f2bf_rne(b.z) | (f2bf_rne(b.w) << 16);
  *(uint4*)&out[(size_t)i * 8] = o;
}

__global__ void gat_cvtT_bf16(const float* __restrict__ W,
                              ushort* __restrict__ Wt, int K, int Nw) {
  int i = blockIdx.x * blockDim.x + threadIdx.x;
  if (i >= K * Nw) return;
  int n = i / K, k = i - n * K;
  Wt[i] = (ushort)f2bf_rne(W[(size_t)k * Nw + n]);
}

// ------------------------- CSR build -------------------------

__global__ void gat_count_kernel(const int* __restrict__ dst, int E, int N,
                                 int* __restrict__ counts) {
  int i = blockIdx.x * blockDim.x + threadIdx.x;
  int ET = E + N;
  if (i >= ET) return;
  int d = (i < E) ? dst[i] : (i - E);
  atomicAdd(&counts[d], 1);
}

__global__ __launch_bounds__(1024) void gat_scan_kernel(
    const int* __restrict__ counts, int* __restrict__ row_off,
    int* __restrict__ cursor, int n) {
  __shared__ int wsum[16];
  __shared__ int s_carry;
  int tid = threadIdx.x;
  int lane = tid & 63;
  int wid = tid >> 6;
  if (tid == 0) s_carry = 0;
  __syncthreads();
  const int TILE = 4096;
  for (int base = 0; base < n; base += TILE) {
    int idx = base + tid * 4;
    int4 v = {0, 0, 0, 0};
    if (idx + 3 < n) {
      v = *(const int4*)&counts[idx];
    } else {
      if (idx + 0 < n) v.x = counts[idx + 0];
      if (idx + 1 < n) v.y = counts[idx + 1];
      if (idx + 2 < n) v.z = counts[idx + 2];
      if (idx + 3 < n) v.w = counts[idx + 3];
    }
    int t0 = v.x, t1 = t0 + v.y, t2 = t1 + v.z, t3 = t2 + v.w;
    int x = t3;
    #pragma unroll
    for (int off = 1; off < 64; off <<= 1) {
      int y = __shfl_up(x, off, 64);
      if (lane >= off) x += y;
    }
    if (lane == 63) wsum[wid] = x;
    __syncthreads();
    if (tid < 16) {
      int s = wsum[tid];
      #pragma unroll
      for (int off = 1; off < 16; off <<= 1) {
        int y = __shfl_up(s, off, 16);
        if (tid >= off) s += y;
      }
      wsum[tid] = s;
    }
    __syncthreads();
    int carry = s_carry;
    int excl_wave = (wid > 0) ? wsum[wid - 1] : 0;
    int b = carry + excl_wave + (x - t3);
    if (idx + 0 < n) { row_off[idx + 0] = b;      cursor[idx + 0] = b;      }
    if (idx + 1 < n) { row_off[idx + 1] = b + t0; cursor[idx + 1] = b + t0; }
    if (idx + 2 < n) { row_off[idx + 2] = b + t1; cursor[idx + 2] = b + t1; }
    if (idx + 3 < n) { row_off[idx + 3] = b + t2; cursor[idx + 3] = b + t2; }
    __syncthreads();
    if (tid == 1023) s_carry = b + t3;  // carry + tile total
    __syncthreads();
  }
  if (threadIdx.x == 0) row_off[n] = s_carry;
}

__global__ void gat_fill_kernel(const int* __restrict__ src,
                                const int* __restrict__ dst, int E, int N,
                                int* __restrict__ cursor, int* __restrict__ col) {
  int i = blockIdx.x * blockDim.x + threadIdx.x;
  int ET = E + N;
  if (i >= ET) return;
  int s, d;
  if (i < E) { s = src[i]; d = dst[i]; }
  else       { s = d = i - E; }
  int pos = atomicAdd(&cursor[d], 1);
  col[pos] = s;
}

// ------------------------- GEMM (bf16 MFMA) + fused alpha -------------------
// C[M,N] = A[M,K] @ Bt[N,K]^T. BM=128, BK=32, 256 thr = 4 waves.
// WN must be 64 when ALPHA: each wave covers exactly one 64-ch head; epilogue
// computes as/ad = <h_row, a_src/a_dst> via 16-lane shuffle reduce, no atomics.

template <int BN, int WM, int WN, bool WRITE_F32, bool WRITE_BF16, bool ALPHA>
__global__ __launch_bounds__(256) void gat_gemm_bf16(
    const ushort* __restrict__ A, const ushort* __restrict__ Bt,
    float* __restrict__ C, ushort* __restrict__ Cb, int M, int K, int N,
    const float* __restrict__ a_src, const float* __restrict__ a_dst,
    float* __restrict__ as_out, float* __restrict__ ad_out, int H) {
  constexpr int BM = 128, BK = 32;
  constexpr int MR = WM / 16, NR = WN / 16;
  constexpr int WCOLS = BN / WN;
  __shared__ __align__(16) ushort Al[BM][40];
  __shared__ __align__(16) ushort Bl[BN][40];
  int tid = threadIdx.x;
  int lane = tid & 63, wid = tid >> 6;
  int wrow = (wid / WCOLS) * WM, wcol = (wid % WCOLS) * WN;
  int brow = blockIdx.x * BM, bcol = blockIdx.y * BN;
  int r0 = tid >> 2, seg = tid & 3;
  int kg = lane >> 4, rl = lane & 15;
  f32x4 acc[MR][NR] = {};
  for (int k0 = 0; k0 < K; k0 += BK) {
    #pragma unroll
    for (int h = 0; h < BM / 64; ++h) {
      int row = r0 + h * 64;
      int ar = brow + row;
      uint4 v = make_uint4(0u, 0u, 0u, 0u);
      if (ar < M) v = *(const uint4*)&A[(size_t)ar * K + k0 + seg * 8];
      *(uint4*)&Al[row][seg * 8] = v;
    }
    #pragma unroll
    for (int h = 0; h < BN / 64; ++h) {
      int row = r0 + h * 64;
      uint4 v = *(const uint4*)&Bt[(size_t)(bcol + row) * K + k0 + seg * 8];
      *(uint4*)&Bl[row][seg * 8] = v;
    }
    __syncthreads();
    bf16x8 af[MR], bfr[NR];
    #pragma unroll
    for (int m = 0; m < MR; ++m)
      af[m] = *(const bf16x8*)&Al[wrow + m * 16 + rl][kg * 8];
    #pragma unroll
    for (int n = 0; n < NR; ++n)
      bfr[n] = *(const bf16x8*)&Bl[wcol + n * 16 + rl][kg * 8];
    #pragma unroll
    for (int m = 0; m < MR; ++m)
      #pragma unroll
      for (int n = 0; n < NR; ++n)
        acc[m][n] = __builtin_amdgcn_mfma_f32_16x16x32_bf16(
            af[m], bfr[n], acc[m][n], 0, 0, 0);
    __syncthreads();
  }
  int orow = kg * 4;
  #pragma unroll
  for (int m = 0; m < MR; ++m) {
    #pragma unroll
    for (int j = 0; j < 4; ++j) {
      int r = brow + wrow + m * 16 + orow + j;
      if (r < M) {
        #pragma unroll
        for (int n = 0; n < NR; ++n) {
          int c = bcol + wcol + n * 16 + rl;
          float v = acc[m][n][j];
          if constexpr (WRITE_F32) C[(size_t)r * N + c] = v;
          if constexpr (WRITE_BF16) Cb[(size_t)r * N + c] = (ushort)f2bf_rne(v);
        }
      }
    }
  }
  if constexpr (ALPHA) {
    static_assert(WN == 64, "alpha fusion needs one head per wave");
    int hh = (bcol + wcol) >> 6;  // head owned by this wave
    float asv[NR], adv[NR];
    #pragma unroll
    for (int n = 0; n < NR; ++n) {
      asv[n] = a_src[hh * 64 + n * 16 + rl];
      adv[n] = a_dst[hh * 64 + n * 16 + rl];
    }
    #pragma unroll
    for (int m = 0; m < MR; ++m) {
      #pragma unroll
      for (int j = 0; j < 4; ++j) {
        float ps = 0.f, pd = 0.f;
        #pragma unroll
        for (int n = 0; n < NR; ++n) {
          ps = fmaf(acc[m][n][j], asv[n], ps);
          pd = fmaf(acc[m][n][j], adv[n], pd);
        }
        #pragma unroll
        for (int off = 1; off < 16; off <<= 1) {  // reduce over rl
          ps += __shfl_xor(ps, off, 64);
          pd += __shfl_xor(pd, off, 64);
        }
        int r = brow + wrow + m * 16 + orow + j;
        if (rl == 0 && r < M) {
          as_out[(size_t)r * H + hh] = ps;
          ad_out[(size_t)r * H + hh] = pd;
        }
      }
    }
  }
}

// ------------------------- layer-0 aggregation -------------------------
// WAVE per node, zero barriers; 8-deep pipelined bf16 gather.

__global__ __launch_bounds__(256) void gat_agg0_kernel(
    const unsigned* __restrict__ h0b, const float* __restrict__ as,
    const float* __restrict__ ad, const int* __restrict__ row_off,
    const int* __restrict__ col, const float* __restrict__ bias,
    ushort* __restrict__ x1b, int N) {
  __shared__ int scol[4][CAP0];
  __shared__ float wt[4][CAP0][4];  // [wid][edge][head]
  int lane = threadIdx.x & 63;
  int wid = threadIdx.x >> 6;
  int n = blockIdx.x * 4 + wid;
  if (n >= N) return;  // whole wave exits; no barriers
  int beg = row_off[n];
  int deg = row_off[n + 1] - beg;
  int degc = deg < CAP0 ? deg : CAP0;
  for (int jj = lane; jj < degc; jj += 64) scol[wid][jj] = col[beg + jj];

  int q = lane >> 4, slot = lane & 15;
  float adv = ad[n * 4 + q];

  float m = -INFINITY;
  for (int jj = slot; jj < deg; jj += 16) {
    int s = (jj < CAP0) ? scol[wid][jj] : col[beg + jj];
    float e = as[s * 4 + q] + adv;
    e = (e > 0.f) ? e : NEG_SLOPE * e;
    if (jj < CAP0) wt[wid][jj][q] = e;
    m = fmaxf(m, e);
  }
  #pragma unroll
  for (int off = 8; off; off >>= 1) m = fmaxf(m, __shfl_xor(m, off, 64));

  float dsum = 0.f;
  for (int jj = slot; jj < deg; jj += 16) {
    float e;
    if (jj < CAP0) {
      e = wt[wid][jj][q];
    } else {
      int s = col[beg + jj];
      e = as[s * 4 + q] + adv;
      e = (e > 0.f) ? e : NEG_SLOPE * e;
    }
    float w = __expf(e - m);
    if (jj < CAP0) wt[wid][jj][q] = w;
    dsum += w;
  }
  #pragma unroll
  for (int off = 8; off; off >>= 1) dsum += __shfl_xor(dsum, off, 64);
  float inv = 1.f / (dsum + 1e-16f);

  float4 acc = make_float4(0.f, 0.f, 0.f, 0.f);
  int c2 = lane * 2;
  if (deg <= CAP0) {
    int jj = 0;
    for (; jj + 8 <= deg; jj += 8) {
      int s0 = __builtin_amdgcn_readfirstlane(scol[wid][jj + 0]);
      int s1 = __builtin_amdgcn_readfirstlane(scol[wid][jj + 1]);
      int s2 = __builtin_amdgcn_readfirstlane(scol[wid][jj + 2]);
      int s3 = __builtin_amdgcn_readfirstlane(scol[wid][jj + 3]);
      int s4 = __builtin_amdgcn_readfirstlane(scol[wid][jj + 4]);
      int s5 = __builtin_amdgcn_readfirstlane(scol[wid][jj + 5]);
      int s6 = __builtin_amdgcn_readfirstlane(scol[wid][jj + 6]);
      int s7 = __builtin_amdgcn_readfirstlane(scol[wid][jj + 7]);
      uint2 v0 = *(const uint2*)(h0b + (size_t)s0 * 128 + c2);
      uint2 v1 = *(const uint2*)(h0b + (size_t)s1 * 128 + c2);
      uint2 v2 = *(const uint2*)(h0b + (size_t)s2 * 128 + c2);
      uint2 v3 = *(const uint2*)(h0b + (size_t)s3 * 128 + c2);
      uint2 v4 = *(const uint2*)(h0b + (size_t)s4 * 128 + c2);
      uint2 v5 = *(const uint2*)(h0b + (size_t)s5 * 128 + c2);
      uint2 v6 = *(const uint2*)(h0b + (size_t)s6 * 128 + c2);
      uint2 v7 = *(const uint2*)(h0b + (size_t)s7 * 128 + c2);
      float w0 = wt[wid][jj + 0][q];
      float w1 = wt[wid][jj + 1][q];
      float w2 = wt[wid][jj + 2][q];
      float w3 = wt[wid][jj + 3][q];
      float w4 = wt[wid][jj + 4][q];
      float w5 = wt[wid][jj + 5][q];
      float w6 = wt[wid][jj + 6][q];
      float w7 = wt[wid][jj + 7][q];
      fma4(acc, w0, v0); fma4(acc, w1, v1); fma4(acc, w2, v2); fma4(acc, w3, v3);
      fma4(acc, w4, v4); fma4(acc, w5, v5); fma4(acc, w6, v6); fma4(acc, w7, v7);
    }
    for (; jj < deg; ++jj) {
      int s = __builtin_amdgcn_readfirstlane(scol[wid][jj]);
      uint2 v = *(const uint2*)(h0b + (size_t)s * 128 + c2);
      fma4(acc, wt[wid][jj][q], v);
    }
  } else {  // huge-degree fallback
    for (int jj = 0; jj < deg; ++jj) {
      int s = (jj < CAP0) ? scol[wid][jj] : col[beg + jj];
      s = __builtin_amdgcn_readfirstlane(s);
      uint2 v = *(const uint2*)(h0b + (size_t)s * 128 + c2);
      float w;
      if (jj < CAP0) {
        w = wt[wid][jj][q];
      } else {
        float e = as[s * 4 + q] + adv;
        e = (e > 0.f) ? e : NEG_SLOPE * e;
        w = __expf(e - m);
      }
      fma4(acc, w, v);
    }
  }

  int c0 = lane * 4;
  float4 bv = *(const float4*)&bias[c0];
  float o0 = acc.x * inv + bv.x;
  float o1 = acc.y * inv + bv.y;
  float o2 = acc.z * inv + bv.z;
  float o3 = acc.w * inv + bv.w;
  o0 = (o0 > 0.f) ? o0 : (__expf(o0) - 1.f);
  o1 = (o1 > 0.f) ? o1 : (__expf(o1) - 1.f);
  o2 = (o2 > 0.f) ? o2 : (__expf(o2) - 1.f);
  o3 = (o3 > 0.f) ? o3 : (__expf(o3) - 1.f);
  uint2 p;
  p.x = f2bf_rne(o0) | (f2bf_rne(o1) << 16);
  p.y = f2bf_rne(o2) | (f2bf_rne(o3) << 16);
  *(uint2*)&x1b[(size_t)n * 256 + c0] = p;
}

// ------------------------- layer-1 aggregation -------------------------
// WAVE per node, zero barriers. H=1; 8-deep pipelined bf16 gather.

__global__ __launch_bounds__(256) void gat_agg1_kernel(
    const ushort* __restrict__ h1b, const float* __restrict__ as,
    const float* __restrict__ ad, const int* __restrict__ row_off,
    const int* __restrict__ col, const float* __restrict__ bias,
    float* __restrict__ out, int N) {
  __shared__ int scol[4][CAP1];
  __shared__ float wt[4][CAP1];
  int lane = threadIdx.x & 63;
  int wid = threadIdx.x >> 6;
  int n = blockIdx.x * 4 + wid;
  if (n >= N) return;
  int beg = row_off[n];
  int deg = row_off[n + 1] - beg;
  int degc = deg < CAP1 ? deg : CAP1;
  for (int jj = lane; jj < degc; jj += 64) scol[wid][jj] = col[beg + jj];
  float adv = ad[n];

  float m = -INFINITY;
  for (int jj = lane; jj < deg; jj += 64) {
    int s = (jj < CAP1) ? scol[wid][jj] : col[beg + jj];
    float e = as[s] + adv;
    e = (e > 0.f) ? e : NEG_SLOPE * e;
    if (jj < CAP1) wt[wid][jj] = e;
    m = fmaxf(m, e);
  }
  #pragma unroll
  for (int off = 32; off; off >>= 1) m = fmaxf(m, __shfl_xor(m, off, 64));

  float dsum = 0.f;
  for (int jj = lane; jj < deg; jj += 64) {
    float e;
    if (jj < CAP1) {
      e = wt[wid][jj];
    } else {
      int s = col[beg + jj];
      e = as[s] + adv;
      e = (e > 0.f) ? e : NEG_SLOPE * e;
    }
    float w = __expf(e - m);
    if (jj < CAP1) wt[wid][jj] = w;
    dsum += w;
  }
  #pragma unroll
  for (int off = 32; off; off >>= 1) dsum += __shfl_xor(dsum, off, 64);
  float inv = 1.f / (dsum + 1e-16f);

  float acc = 0.f;
  if (deg <= CAP1) {
    int jj = 0;
    for (; jj + 8 <= deg; jj += 8) {
      int s0 = __builtin_amdgcn_readfirstlane(scol[wid][jj + 0]);
      int s1 = __builtin_amdgcn_readfirstlane(scol[wid][jj + 1]);
      int s2 = __builtin_amdgcn_readfirstlane(scol[wid][jj + 2]);
      int s3 = __builtin_amdgcn_readfirstlane(scol[wid][jj + 3]);
      int s4 = __builtin_amdgcn_readfirstlane(scol[wid][jj + 4]);
      int s5 = __builtin_amdgcn_readfirstlane(scol[wid][jj + 5]);
      int s6 = __builtin_amdgcn_readfirstlane(scol[wid][jj + 6]);
      int s7 = __builtin_amdgcn_readfirstlane(scol[wid][jj + 7]);
      float v0 = bf2f(h1b[(size_t)s0 * 64 + lane]);
      float v1 = bf2f(h1b[(size_t)s1 * 64 + lane]);
      float v2 = bf2f(h1b[(size_t)s2 * 64 + lane]);
      float v3 = bf2f(h1b[(size_t)s3 * 64 + lane]);
      float v4 = bf2f(h1b[(size_t)s4 * 64 + lane]);
      float v5 = bf2f(h1b[(size_t)s5 * 64 + lane]);
      float v6 = bf2f(h1b[(size_t)s6 * 64 + lane]);
      float v7 = bf2f(h1b[(size_t)s7 * 64 + lane]);
      acc = fmaf(wt[wid][jj + 0], v0, acc);
      acc = fmaf(wt[wid][jj + 1], v1, acc);
      acc = fmaf(wt[wid][jj + 2], v2, acc);
      acc = fmaf(wt[wid][jj + 3], v3, acc);
      acc = fmaf(wt[wid][jj + 4], v4, acc);
      acc = fmaf(wt[wid][jj + 5], v5, acc);
      acc = fmaf(wt[wid][jj + 6], v6, acc);
      acc = fmaf(wt[wid][jj + 7], v7, acc);
    }
    for (; jj < deg; ++jj) {
      int s = __builtin_amdgcn_readfirstlane(scol[wid][jj]);
      acc = fmaf(wt[wid][jj], bf2f(h1b[(size_t)s * 64 + lane]), acc);
    }
  } else {
    for (int jj = 0; jj < deg; ++jj) {
      int s = (jj < CAP1) ? scol[wid][jj] : col[beg + jj];
      s = __builtin_amdgcn_readfirstlane(s);
      float v = bf2f(h1b[(size_t)s * 64 + lane]);
      float w;
      if (jj < CAP1) {
        w = wt[wid][jj];
      } else {
        float e = as[s] + adv;
        e = (e > 0.f) ? e : NEG_SLOPE * e;
        w = __expf(e - m);
      }
      acc = fmaf(w, v, acc);
    }
  }
  out[(size_t)n * 64 + lane] = acc * inv + bias[lane];
}

// ------------------------- launch -------------------------

extern "C" void kernel_launch(void* const* d_in, const int* in_sizes, int n_in,
                              void* d_out, int out_size, void* d_ws, size_t ws_size,
                              hipStream_t stream) {
  const float* x        = (const float*)d_in[0];
  const int*   eidx     = (const int*)d_in[1];
  const float* W0       = (const float*)d_in[2];
  const float* att_src0 = (const float*)d_in[3];
  const float* att_dst0 = (const float*)d_in[4];
  const float* b0       = (const float*)d_in[5];
  const float* W1       = (const float*)d_in[6];
  const float* att_src1 = (const float*)d_in[7];
  const float* att_dst1 = (const float*)d_in[8];
  const float* b1       = (const float*)d_in[9];
  float* out = (float*)d_out;

  const int F_IN = 256, HID = 256, H = 4, C = 64;
  const int N = in_sizes[0] / F_IN;       // 50000
  const int E = in_sizes[1] / 2;          // 800000
  const int ET = E + N;                   // with self-loops

  const int* src = eidx;
  const int* dst = eidx + E;

  // workspace layout
  char* w = (char*)d_ws;
  auto take = [&](size_t bytes) {
    char* p = w;
    w += (bytes + 255) & ~(size_t)255;
    return p;
  };
  ushort* xb      = (ushort*)take((size_t)N * F_IN * 2);
  ushort* W0t     = (ushort*)take((size_t)F_IN * HID * 2);
  ushort* W1t     = (ushort*)take((size_t)HID * C * 2);
  ushort* h0b     = (ushort*)take((size_t)N * HID * 2);
  ushort* x1b     = (ushort*)take((size_t)N * HID * 2);
  ushort* h1b     = (ushort*)take((size_t)N * C * 2);
  float*  as0     = (float*)take((size_t)N * H * 4);
  float*  ad0     = (float*)take((size_t)N * H * 4);
  float*  as1     = (float*)take((size_t)N * 4);
  float*  ad1     = (float*)take((size_t)N * 4);
  int*    row_off = (int*)take((size_t)(N + 1) * 4);
  int*    cursor  = (int*)take((size_t)N * 4);
  int*    counts  = (int*)take((size_t)N * 4);
  int*    col     = (int*)take((size_t)ET * 4);

  // --- converts ---
  {
    int n8 = N * F_IN / 8;
    gat_cvt_bf16<<<(n8 + 255) / 256, 256, 0, stream>>>(x, xb, n8);
    gat_cvtT_bf16<<<(F_IN * HID + 255) / 256, 256, 0, stream>>>(W0, W0t, F_IN, HID);
    gat_cvtT_bf16<<<(HID * C + 255) / 256, 256, 0, stream>>>(W1, W1t, HID, C);
  }

  // --- CSR build ---
  (void)hipMemsetAsync(counts, 0, (size_t)N * 4, stream);
  {
    int blocks = (ET + 255) / 256;
    gat_count_kernel<<<blocks, 256, 0, stream>>>(dst, E, N, counts);
    gat_scan_kernel<<<1, 1024, 0, stream>>>(counts, row_off, cursor, N);
    gat_fill_kernel<<<blocks, 256, 0, stream>>>(src, dst, E, N, cursor, col);
  }

  // --- layer 0: GEMM + fused alpha ---
  {
    dim3 grid((N + 127) / 128, HID / 128);
    gat_gemm_bf16<128, 64, 64, false, true, true>
        <<<grid, 256, 0, stream>>>(xb, W0t, nullptr, h0b, N, F_IN, HID,
                                   att_src0, att_dst0, as0, ad0, H);
  }
  gat_agg0_kernel<<<(N + 3) / 4, 256, 0, stream>>>((const unsigned*)h0b, as0,
                                                   ad0, row_off, col, b0, x1b, N);

  // --- layer 1: GEMM (bf16 out) + fused alpha ---
  {
    dim3 grid((N + 127) / 128, C / 64);
    gat_gemm_bf16<64, 32, 64, false, true, true>
        <<<grid, 256, 0, stream>>>(x1b, W1t, nullptr, h1b, N, HID, C,
                                   att_src1, att_dst1, as1, ad1, 1);
  }
  gat_agg1_kernel<<<(N + 3) / 4, 256, 0, stream>>>(h1b, as1, ad1, row_off, col,
                                                   b1, out, N);
}

// Round 13
// 265.141 us; speedup vs baseline: 2.3533x; 1.0586x over previous
//
#include <hip/hip_runtime.h>
#include <hip/hip_bf16.h>
#include <math.h>

// ---------------------------------------------------------------------------
// GAT 2-layer forward. bf16 MFMA GEMMs + bf16 gather tables, fp32 softmax.
// R5: bf16 MFMA GEMMs. R8: wave-per-node zero-barrier agg.
// R9: 4-deep pipelined gather (agg0 86.6->66us). R10/11: alpha fused into
// GEMM epilogues, bf16 h1b (325->280.7us; 8-deep agg0 neutral -> reverted).
// R12: agg1 edge-pair gather (2 edges/iter, 4B/lane, shfl_xor(32) combine);
//      x-convert fused into GEMM0 staging (CVT_A, BN=256, 512thr, 1 A-pass);
//      agg0 back to 4-deep.
// ---------------------------------------------------------------------------

#define NEG_SLOPE 0.2f
#define CAP0 128
#define CAP1 128

typedef __attribute__((ext_vector_type(8))) short bf16x8;
typedef __attribute__((ext_vector_type(4))) float f32x4;

static __device__ __forceinline__ unsigned f2bf_rne(float f) {
  unsigned u = __float_as_uint(f);
  return (u + 0x7fffu + ((u >> 16) & 1u)) >> 16;  // round-to-nearest-even
}
static __device__ __forceinline__ float bf2f(unsigned u16) {
  return __uint_as_float(u16 << 16);
}
static __device__ __forceinline__ void fma4(float4& acc, float w, uint2 v) {
  acc.x = fmaf(w, __uint_as_float(v.x << 16), acc.x);
  acc.y = fmaf(w, __uint_as_float(v.x & 0xffff0000u), acc.y);
  acc.z = fmaf(w, __uint_as_float(v.y << 16), acc.z);
  acc.w = fmaf(w, __uint_as_float(v.y & 0xffff0000u), acc.w);
}

// ------------------------- converts (weights only) -------------------------

__global__ void gat_cvtT_bf16(const float* __restrict__ W,
                              ushort* __restrict__ Wt, int K, int Nw) {
  int i = blockIdx.x * blockDim.x + threadIdx.x;
  if (i >= K * Nw) return;
  int n = i / K, k = i - n * K;
  Wt[i] = (ushort)f2bf_rne(W[(size_t)k * Nw + n]);
}

// ------------------------- CSR build -------------------------

__global__ void gat_count_kernel(const int* __restrict__ dst, int E, int N,
                                 int* __restrict__ counts) {
  int i = blockIdx.x * blockDim.x + threadIdx.x;
  int ET = E + N;
  if (i >= ET) return;
  int d = (i < E) ? dst[i] : (i - E);
  atomicAdd(&counts[d], 1);
}

__global__ __launch_bounds__(1024) void gat_scan_kernel(
    const int* __restrict__ counts, int* __restrict__ row_off,
    int* __restrict__ cursor, int n) {
  __shared__ int wsum[16];
  __shared__ int s_carry;
  int tid = threadIdx.x;
  int lane = tid & 63;
  int wid = tid >> 6;
  if (tid == 0) s_carry = 0;
  __syncthreads();
  const int TILE = 4096;
  for (int base = 0; base < n; base += TILE) {
    int idx = base + tid * 4;
    int4 v = {0, 0, 0, 0};
    if (idx + 3 < n) {
      v = *(const int4*)&counts[idx];
    } else {
      if (idx + 0 < n) v.x = counts[idx + 0];
      if (idx + 1 < n) v.y = counts[idx + 1];
      if (idx + 2 < n) v.z = counts[idx + 2];
      if (idx + 3 < n) v.w = counts[idx + 3];
    }
    int t0 = v.x, t1 = t0 + v.y, t2 = t1 + v.z, t3 = t2 + v.w;
    int x = t3;
    #pragma unroll
    for (int off = 1; off < 64; off <<= 1) {
      int y = __shfl_up(x, off, 64);
      if (lane >= off) x += y;
    }
    if (lane == 63) wsum[wid] = x;
    __syncthreads();
    if (tid < 16) {
      int s = wsum[tid];
      #pragma unroll
      for (int off = 1; off < 16; off <<= 1) {
        int y = __shfl_up(s, off, 16);
        if (tid >= off) s += y;
      }
      wsum[tid] = s;
    }
    __syncthreads();
    int carry = s_carry;
    int excl_wave = (wid > 0) ? wsum[wid - 1] : 0;
    int b = carry + excl_wave + (x - t3);
    if (idx + 0 < n) { row_off[idx + 0] = b;      cursor[idx + 0] = b;      }
    if (idx + 1 < n) { row_off[idx + 1] = b + t0; cursor[idx + 1] = b + t0; }
    if (idx + 2 < n) { row_off[idx + 2] = b + t1; cursor[idx + 2] = b + t1; }
    if (idx + 3 < n) { row_off[idx + 3] = b + t2; cursor[idx + 3] = b + t2; }
    __syncthreads();
    if (tid == 1023) s_carry = b + t3;  // carry + tile total
    __syncthreads();
  }
  if (threadIdx.x == 0) row_off[n] = s_carry;
}

__global__ void gat_fill_kernel(const int* __restrict__ src,
                                const int* __restrict__ dst, int E, int N,
                                int* __restrict__ cursor, int* __restrict__ col) {
  int i = blockIdx.x * blockDim.x + threadIdx.x;
  int ET = E + N;
  if (i >= ET) return;
  int s, d;
  if (i < E) { s = src[i]; d = dst[i]; }
  else       { s = d = i - E; }
  int pos = atomicAdd(&cursor[d], 1);
  col[pos] = s;
}

// ------------------------- GEMM (bf16 MFMA) + fused alpha -------------------
// C[M,N] = A[M,K] @ Bt[N,K]^T. BM=128, BK=32. THREADS/64 waves, WM x WN each.
// CVT_A: A is fp32, converted to bf16 in-register during LDS staging.
// ALPHA (needs WN==64): epilogue computes as/ad via 16-lane shuffle reduce.

template <int THREADS, int BN, int WM, int WN, bool WRITE_BF16, bool ALPHA,
          bool CVT_A>
__global__ __launch_bounds__(THREADS) void gat_gemm_bf16(
    const float* __restrict__ Af, const ushort* __restrict__ Ab,
    const ushort* __restrict__ Bt, ushort* __restrict__ Cb, int M, int K,
    int N, const float* __restrict__ a_src, const float* __restrict__ a_dst,
    float* __restrict__ as_out, float* __restrict__ ad_out, int H) {
  constexpr int BM = 128, BK = 32;
  constexpr int MR = WM / 16, NR = WN / 16;
  constexpr int WCOLS = BN / WN;
  constexpr int RPP = THREADS / 4;  // rows staged per pass (4 thr x 8 elem)
  static_assert(BM % RPP == 0 && BN % RPP == 0, "staging");
  static_assert((BM / WM) * (BN / WN) == THREADS / 64, "wave tiling");
  __shared__ __align__(16) ushort Al[BM][40];
  __shared__ __align__(16) ushort Bl[BN][40];
  int tid = threadIdx.x;
  int lane = tid & 63, wid = tid >> 6;
  int wrow = (wid / WCOLS) * WM, wcol = (wid % WCOLS) * WN;
  int brow = blockIdx.x * BM, bcol = blockIdx.y * BN;
  int r0 = tid >> 2, seg = tid & 3;
  int kg = lane >> 4, rl = lane & 15;
  f32x4 acc[MR][NR] = {};
  for (int k0 = 0; k0 < K; k0 += BK) {
    #pragma unroll
    for (int h = 0; h < BM / RPP; ++h) {
      int row = r0 + h * RPP;
      int ar = brow + row;
      uint4 v = make_uint4(0u, 0u, 0u, 0u);
      if (ar < M) {
        if constexpr (CVT_A) {
          float4 a0 = *(const float4*)&Af[(size_t)ar * K + k0 + seg * 8];
          float4 a1 = *(const float4*)&Af[(size_t)ar * K + k0 + seg * 8 + 4];
          v.x = f2bf_rne(a0.x) | (f2bf_rne(a0.y) << 16);
          v.y = f2bf_rne(a0.z) | (f2bf_rne(a0.w) << 16);
          v.z = f2bf_rne(a1.x) | (f2bf_rne(a1.y) << 16);
          v.w = f2bf_rne(a1.z) | (f2bf_rne(a1.w) << 16);
        } else {
          v = *(const uint4*)&Ab[(size_t)ar * K + k0 + seg * 8];
        }
      }
      *(uint4*)&Al[row][seg * 8] = v;
    }
    #pragma unroll
    for (int h = 0; h < BN / RPP; ++h) {
      int row = r0 + h * RPP;
      uint4 v = *(const uint4*)&Bt[(size_t)(bcol + row) * K + k0 + seg * 8];
      *(uint4*)&Bl[row][seg * 8] = v;
    }
    __syncthreads();
    bf16x8 af[MR], bfr[NR];
    #pragma unroll
    for (int m = 0; m < MR; ++m)
      af[m] = *(const bf16x8*)&Al[wrow + m * 16 + rl][kg * 8];
    #pragma unroll
    for (int n = 0; n < NR; ++n)
      bfr[n] = *(const bf16x8*)&Bl[wcol + n * 16 + rl][kg * 8];
    #pragma unroll
    for (int m = 0; m < MR; ++m)
      #pragma unroll
      for (int n = 0; n < NR; ++n)
        acc[m][n] = __builtin_amdgcn_mfma_f32_16x16x32_bf16(
            af[m], bfr[n], acc[m][n], 0, 0, 0);
    __syncthreads();
  }
  int orow = kg * 4;
  #pragma unroll
  for (int m = 0; m < MR; ++m) {
    #pragma unroll
    for (int j = 0; j < 4; ++j) {
      int r = brow + wrow + m * 16 + orow + j;
      if (r < M) {
        #pragma unroll
        for (int n = 0; n < NR; ++n) {
          int c = bcol + wcol + n * 16 + rl;
          float v = acc[m][n][j];
          if constexpr (WRITE_BF16) Cb[(size_t)r * N + c] = (ushort)f2bf_rne(v);
        }
      }
    }
  }
  if constexpr (ALPHA) {
    static_assert(WN == 64, "alpha fusion needs one head per wave");
    int hh = (bcol + wcol) >> 6;  // head owned by this wave
    float asv[NR], adv[NR];
    #pragma unroll
    for (int n = 0; n < NR; ++n) {
      asv[n] = a_src[hh * 64 + n * 16 + rl];
      adv[n] = a_dst[hh * 64 + n * 16 + rl];
    }
    #pragma unroll
    for (int m = 0; m < MR; ++m) {
      #pragma unroll
      for (int j = 0; j < 4; ++j) {
        float ps = 0.f, pd = 0.f;
        #pragma unroll
        for (int n = 0; n < NR; ++n) {
          ps = fmaf(acc[m][n][j], asv[n], ps);
          pd = fmaf(acc[m][n][j], adv[n], pd);
        }
        #pragma unroll
        for (int off = 1; off < 16; off <<= 1) {  // reduce over rl
          ps += __shfl_xor(ps, off, 64);
          pd += __shfl_xor(pd, off, 64);
        }
        int r = brow + wrow + m * 16 + orow + j;
        if (rl == 0 && r < M) {
          as_out[(size_t)r * H + hh] = ps;
          ad_out[(size_t)r * H + hh] = pd;
        }
      }
    }
  }
}

// ------------------------- layer-0 aggregation -------------------------
// WAVE per node, zero barriers; 4-deep pipelined bf16 gather (R9 config).

__global__ __launch_bounds__(256) void gat_agg0_kernel(
    const unsigned* __restrict__ h0b, const float* __restrict__ as,
    const float* __restrict__ ad, const int* __restrict__ row_off,
    const int* __restrict__ col, const float* __restrict__ bias,
    ushort* __restrict__ x1b, int N) {
  __shared__ int scol[4][CAP0];
  __shared__ float wt[4][CAP0][4];  // [wid][edge][head]
  int lane = threadIdx.x & 63;
  int wid = threadIdx.x >> 6;
  int n = blockIdx.x * 4 + wid;
  if (n >= N) return;  // whole wave exits; no barriers
  int beg = row_off[n];
  int deg = row_off[n + 1] - beg;
  int degc = deg < CAP0 ? deg : CAP0;
  for (int jj = lane; jj < degc; jj += 64) scol[wid][jj] = col[beg + jj];

  int q = lane >> 4, slot = lane & 15;
  float adv = ad[n * 4 + q];

  float m = -INFINITY;
  for (int jj = slot; jj < deg; jj += 16) {
    int s = (jj < CAP0) ? scol[wid][jj] : col[beg + jj];
    float e = as[s * 4 + q] + adv;
    e = (e > 0.f) ? e : NEG_SLOPE * e;
    if (jj < CAP0) wt[wid][jj][q] = e;
    m = fmaxf(m, e);
  }
  #pragma unroll
  for (int off = 8; off; off >>= 1) m = fmaxf(m, __shfl_xor(m, off, 64));

  float dsum = 0.f;
  for (int jj = slot; jj < deg; jj += 16) {
    float e;
    if (jj < CAP0) {
      e = wt[wid][jj][q];
    } else {
      int s = col[beg + jj];
      e = as[s * 4 + q] + adv;
      e = (e > 0.f) ? e : NEG_SLOPE * e;
    }
    float w = __expf(e - m);
    if (jj < CAP0) wt[wid][jj][q] = w;
    dsum += w;
  }
  #pragma unroll
  for (int off = 8; off; off >>= 1) dsum += __shfl_xor(dsum, off, 64);
  float inv = 1.f / (dsum + 1e-16f);

  float4 acc = make_float4(0.f, 0.f, 0.f, 0.f);
  int c2 = lane * 2;
  if (deg <= CAP0) {
    int jj = 0;
    for (; jj + 4 <= deg; jj += 4) {
      int s0 = __builtin_amdgcn_readfirstlane(scol[wid][jj + 0]);
      int s1 = __builtin_amdgcn_readfirstlane(scol[wid][jj + 1]);
      int s2 = __builtin_amdgcn_readfirstlane(scol[wid][jj + 2]);
      int s3 = __builtin_amdgcn_readfirstlane(scol[wid][jj + 3]);
      uint2 v0 = *(const uint2*)(h0b + (size_t)s0 * 128 + c2);
      uint2 v1 = *(const uint2*)(h0b + (size_t)s1 * 128 + c2);
      uint2 v2 = *(const uint2*)(h0b + (size_t)s2 * 128 + c2);
      uint2 v3 = *(const uint2*)(h0b + (size_t)s3 * 128 + c2);
      float w0 = wt[wid][jj + 0][q];
      float w1 = wt[wid][jj + 1][q];
      float w2 = wt[wid][jj + 2][q];
      float w3 = wt[wid][jj + 3][q];
      fma4(acc, w0, v0); fma4(acc, w1, v1);
      fma4(acc, w2, v2); fma4(acc, w3, v3);
    }
    for (; jj < deg; ++jj) {
      int s = __builtin_amdgcn_readfirstlane(scol[wid][jj]);
      uint2 v = *(const uint2*)(h0b + (size_t)s * 128 + c2);
      fma4(acc, wt[wid][jj][q], v);
    }
  } else {  // huge-degree fallback
    for (int jj = 0; jj < deg; ++jj) {
      int s = (jj < CAP0) ? scol[wid][jj] : col[beg + jj];
      s = __builtin_amdgcn_readfirstlane(s);
      uint2 v = *(const uint2*)(h0b + (size_t)s * 128 + c2);
      float w;
      if (jj < CAP0) {
        w = wt[wid][jj][q];
      } else {
        float e = as[s * 4 + q] + adv;
        e = (e > 0.f) ? e : NEG_SLOPE * e;
        w = __expf(e - m);
      }
      fma4(acc, w, v);
    }
  }

  int c0 = lane * 4;
  float4 bv = *(const float4*)&bias[c0];
  float o0 = acc.x * inv + bv.x;
  float o1 = acc.y * inv + bv.y;
  float o2 = acc.z * inv + bv.z;
  float o3 = acc.w * inv + bv.w;
  o0 = (o0 > 0.f) ? o0 : (__expf(o0) - 1.f);
  o1 = (o1 > 0.f) ? o1 : (__expf(o1) - 1.f);
  o2 = (o2 > 0.f) ? o2 : (__expf(o2) - 1.f);
  o3 = (o3 > 0.f) ? o3 : (__expf(o3) - 1.f);
  uint2 p;
  p.x = f2bf_rne(o0) | (f2bf_rne(o1) << 16);
  p.y = f2bf_rne(o2) | (f2bf_rne(o3) << 16);
  *(uint2*)&x1b[(size_t)n * 256 + c0] = p;
}

// ------------------------- layer-1 aggregation -------------------------
// WAVE per node, zero barriers. Edge-PAIR gather: half-wave (32 lanes) per
// edge, lane reads uint (2 ch, 4B); 4-deep over pairs = 8 edges in flight;
// cross-half shfl_xor(32) combine; float2 output.

__global__ __launch_bounds__(256) void gat_agg1_kernel(
    const ushort* __restrict__ h1b, const float* __restrict__ as,
    const float* __restrict__ ad, const int* __restrict__ row_off,
    const int* __restrict__ col, const float* __restrict__ bias,
    float* __restrict__ out, int N) {
  __shared__ int scol[4][CAP1];
  __shared__ float wt[4][CAP1];
  int lane = threadIdx.x & 63;
  int wid = threadIdx.x >> 6;
  int n = blockIdx.x * 4 + wid;
  if (n >= N) return;
  int beg = row_off[n];
  int deg = row_off[n + 1] - beg;
  int degc = deg < CAP1 ? deg : CAP1;
  for (int jj = lane; jj < degc; jj += 64) scol[wid][jj] = col[beg + jj];
  float adv = ad[n];

  float m = -INFINITY;
  for (int jj = lane; jj < deg; jj += 64) {
    int s = (jj < CAP1) ? scol[wid][jj] : col[beg + jj];
    float e = as[s] + adv;
    e = (e > 0.f) ? e : NEG_SLOPE * e;
    if (jj < CAP1) wt[wid][jj] = e;
    m = fmaxf(m, e);
  }
  #pragma unroll
  for (int off = 32; off; off >>= 1) m = fmaxf(m, __shfl_xor(m, off, 64));

  float dsum = 0.f;
  for (int jj = lane; jj < deg; jj += 64) {
    float e;
    if (jj < CAP1) {
      e = wt[wid][jj];
    } else {
      int s = col[beg + jj];
      e = as[s] + adv;
      e = (e > 0.f) ? e : NEG_SLOPE * e;
    }
    float w = __expf(e - m);
    if (jj < CAP1) wt[wid][jj] = w;
    dsum += w;
  }
  #pragma unroll
  for (int off = 32; off; off >>= 1) dsum += __shfl_xor(dsum, off, 64);
  float inv = 1.f / (dsum + 1e-16f);

  int half = lane >> 5, c = lane & 31;
  float ax = 0.f, ay = 0.f;
  if (deg <= CAP1) {
    int Pf = deg >> 1;  // full pairs
    int t = 0;
    for (; t + 4 <= Pf; t += 4) {
      int j0 = 2 * t + half;
      int s0 = scol[wid][j0 + 0];
      int s1 = scol[wid][j0 + 2];
      int s2 = scol[wid][j0 + 4];
      int s3 = scol[wid][j0 + 6];
      unsigned v0 = *(const unsigned*)(h1b + (size_t)s0 * 64 + c * 2);
      unsigned v1 = *(const unsigned*)(h1b + (size_t)s1 * 64 + c * 2);
      unsigned v2 = *(const unsigned*)(h1b + (size_t)s2 * 64 + c * 2);
      unsigned v3 = *(const unsigned*)(h1b + (size_t)s3 * 64 + c * 2);
      float w0 = wt[wid][j0 + 0];
      float w1 = wt[wid][j0 + 2];
      float w2 = wt[wid][j0 + 4];
      float w3 = wt[wid][j0 + 6];
      ax = fmaf(w0, bf2f(v0 & 0xffffu), ax);
      ay = fmaf(w0, bf2f(v0 >> 16), ay);
      ax = fmaf(w1, bf2f(v1 & 0xffffu), ax);
      ay = fmaf(w1, bf2f(v1 >> 16), ay);
      ax = fmaf(w2, bf2f(v2 & 0xffffu), ax);
      ay = fmaf(w2, bf2f(v2 >> 16), ay);
      ax = fmaf(w3, bf2f(v3 & 0xffffu), ax);
      ay = fmaf(w3, bf2f(v3 >> 16), ay);
    }
    for (; t < Pf; ++t) {
      int j0 = 2 * t + half;
      int s = scol[wid][j0];
      unsigned v = *(const unsigned*)(h1b + (size_t)s * 64 + c * 2);
      float w = wt[wid][j0];
      ax = fmaf(w, bf2f(v & 0xffffu), ax);
      ay = fmaf(w, bf2f(v >> 16), ay);
    }
    if (deg & 1) {  // odd tail edge: half 0 does it, half 1 gets w=0
      int jj = deg - 1;
      int s = scol[wid][jj];
      unsigned v = *(const unsigned*)(h1b + (size_t)s * 64 + c * 2);
      float w = (half == 0) ? wt[wid][jj] : 0.f;
      ax = fmaf(w, bf2f(v & 0xffffu), ax);
      ay = fmaf(w, bf2f(v >> 16), ay);
    }
  } else {  // huge-degree fallback (pairs, weights recomputed past CAP)
    int P = (deg + 1) >> 1;
    for (int t = 0; t < P; ++t) {
      int jj = 2 * t + half;
      int jc = jj < deg ? jj : (deg - 1);
      int s = (jc < CAP1) ? scol[wid][jc] : col[beg + jc];
      unsigned v = *(const unsigned*)(h1b + (size_t)s * 64 + c * 2);
      float w;
      if (jc < CAP1) {
        w = wt[wid][jc];
      } else {
        float e = as[s] + adv;
        e = (e > 0.f) ? e : NEG_SLOPE * e;
        w = __expf(e - m);
      }
      if (jj >= deg) w = 0.f;
      ax = fmaf(w, bf2f(v & 0xffffu), ax);
      ay = fmaf(w, bf2f(v >> 16), ay);
    }
  }
  ax += __shfl_xor(ax, 32, 64);
  ay += __shfl_xor(ay, 32, 64);
  if (half == 0) {
    float2 bv = *(const float2*)&bias[c * 2];
    float2 o;
    o.x = ax * inv + bv.x;
    o.y = ay * inv + bv.y;
    *(float2*)&out[(size_t)n * 64 + c * 2] = o;
  }
}

// ------------------------- launch -------------------------

extern "C" void kernel_launch(void* const* d_in, const int* in_sizes, int n_in,
                              void* d_out, int out_size, void* d_ws, size_t ws_size,
                              hipStream_t stream) {
  const float* x        = (const float*)d_in[0];
  const int*   eidx     = (const int*)d_in[1];
  const float* W0       = (const float*)d_in[2];
  const float* att_src0 = (const float*)d_in[3];
  const float* att_dst0 = (const float*)d_in[4];
  const float* b0       = (const float*)d_in[5];
  const float* W1       = (const float*)d_in[6];
  const float* att_src1 = (const float*)d_in[7];
  const float* att_dst1 = (const float*)d_in[8];
  const float* b1       = (const float*)d_in[9];
  float* out = (float*)d_out;

  const int F_IN = 256, HID = 256, H = 4, C = 64;
  const int N = in_sizes[0] / F_IN;       // 50000
  const int E = in_sizes[1] / 2;          // 800000
  const int ET = E + N;                   // with self-loops

  const int* src = eidx;
  const int* dst = eidx + E;

  // workspace layout
  char* w = (char*)d_ws;
  auto take = [&](size_t bytes) {
    char* p = w;
    w += (bytes + 255) & ~(size_t)255;
    return p;
  };
  ushort* W0t     = (ushort*)take((size_t)F_IN * HID * 2);
  ushort* W1t     = (ushort*)take((size_t)HID * C * 2);
  ushort* h0b     = (ushort*)take((size_t)N * HID * 2);
  ushort* x1b     = (ushort*)take((size_t)N * HID * 2);
  ushort* h1b     = (ushort*)take((size_t)N * C * 2);
  float*  as0     = (float*)take((size_t)N * H * 4);
  float*  ad0     = (float*)take((size_t)N * H * 4);
  float*  as1     = (float*)take((size_t)N * 4);
  float*  ad1     = (float*)take((size_t)N * 4);
  int*    row_off = (int*)take((size_t)(N + 1) * 4);
  int*    cursor  = (int*)take((size_t)N * 4);
  int*    counts  = (int*)take((size_t)N * 4);
  int*    col     = (int*)take((size_t)ET * 4);

  // --- weight converts ---
  gat_cvtT_bf16<<<(F_IN * HID + 255) / 256, 256, 0, stream>>>(W0, W0t, F_IN, HID);
  gat_cvtT_bf16<<<(HID * C + 255) / 256, 256, 0, stream>>>(W1, W1t, HID, C);

  // --- CSR build ---
  (void)hipMemsetAsync(counts, 0, (size_t)N * 4, stream);
  {
    int blocks = (ET + 255) / 256;
    gat_count_kernel<<<blocks, 256, 0, stream>>>(dst, E, N, counts);
    gat_scan_kernel<<<1, 1024, 0, stream>>>(counts, row_off, cursor, N);
    gat_fill_kernel<<<blocks, 256, 0, stream>>>(src, dst, E, N, cursor, col);
  }

  // --- layer 0: GEMM (fp32 A converted inline) + fused alpha ---
  {
    dim3 grid((N + 127) / 128, HID / 256);
    gat_gemm_bf16<512, 256, 64, 64, true, true, true>
        <<<grid, 512, 0, stream>>>(x, nullptr, W0t, h0b, N, F_IN, HID,
                                   att_src0, att_dst0, as0, ad0, H);
  }
  gat_agg0_kernel<<<(N + 3) / 4, 256, 0, stream>>>((const unsigned*)h0b, as0,
                                                   ad0, row_off, col, b0, x1b, N);

  // --- layer 1: GEMM (bf16 A) + fused alpha ---
  {
    dim3 grid((N + 127) / 128, C / 64);
    gat_gemm_bf16<256, 64, 32, 64, true, true, false>
        <<<grid, 256, 0, stream>>>(nullptr, x1b, W1t, h1b, N, HID, C,
                                   att_src1, att_dst1, as1, ad1, 1);
  }
  gat_agg1_kernel<<<(N + 3) / 4, 256, 0, stream>>>(h1b, as1, ad1, row_off, col,
                                                   b1, out, N);
}